// Round 2
// baseline (4631.308 us; speedup 1.0000x reference)
//
#include <hip/hip_runtime.h>
#include <stdint.h>
#include <math.h>

#define DEVI __device__ __forceinline__

// Problem constants (B,T,H,E fixed by the reference setup)
constexpr int TB  = 2;
constexpr int TT  = 4096;
constexpr int TH  = 8;
constexpr int TE  = 64;
constexpr int TBH = 16;   // B*H
constexpr int TM  = 256;  // performer features
constexpr int TNH = 4;    // hash rounds
constexpr float C_TEMP  = 0.125f;                 // 1/sqrt(E)
constexpr float C_DN    = 0.35355339059327373f;   // sqrt(temp)
constexpr float C_RATIO = 0.0625f;                // M^-0.5

// ---------------- workspace layout ----------------
constexpr size_t algn(size_t x){ return (x + 255) & ~(size_t)255; }
constexpr size_t OFF_QN2F = 0;
constexpr size_t OFF_KN2F = algn(OFF_QN2F + (size_t)TBH*TT*4);
constexpr size_t OFF_QN2D = algn(OFF_KN2F + (size_t)TBH*TT*4);
constexpr size_t OFF_KN2D = algn(OFF_QN2D + (size_t)TBH*TT*8);
constexpr size_t OFF_MQK2 = algn(OFF_KN2D + (size_t)TBH*TT*8);
constexpr size_t OFF_QH   = algn(OFF_MQK2 + (size_t)TBH*8);
constexpr size_t OFF_KH   = algn(OFF_QH   + (size_t)TNH*TBH*TT*8);
constexpr size_t OFF_QPOS = algn(OFF_KH   + (size_t)TNH*TBH*TT*8);
constexpr size_t OFF_KPOS = algn(OFF_QPOS + (size_t)TNH*TBH*TT*4);
constexpr size_t OFF_QREV = algn(OFF_KPOS + (size_t)TNH*TBH*TT*4);
constexpr size_t OFF_KREV = algn(OFF_QREV + (size_t)TNH*TBH*TT*4);
constexpr size_t OFF_KLSP = algn(OFF_KREV + (size_t)TNH*TBH*TT*4);
constexpr size_t OFF_KLS  = algn(OFF_KLSP + (size_t)TBH*128*4);
constexpr size_t OFF_QP   = algn(OFF_KLS  + (size_t)TBH*4);
constexpr size_t OFF_KP   = algn(OFF_QP   + (size_t)TBH*TT*TM*4);   // fp32
constexpr size_t OFF_PLS  = algn(OFF_KP   + (size_t)TBH*TT*TM*4);   // fp32
constexpr size_t OFF_KSUM = algn(OFF_PLS  + (size_t)TBH*TT*4);
constexpr size_t OFF_KV   = algn(OFF_KSUM + (size_t)TBH*TM*4);
constexpr size_t OFF_OT   = algn(OFF_KV   + (size_t)TBH*TM*TE*4);
constexpr size_t OFF_LSET = algn(OFF_OT   + (size_t)TNH*TBH*TT*TE*4);
constexpr size_t OFF_DSUM = algn(OFF_LSET + (size_t)TNH*TBH*TT*4);
constexpr size_t WS_NEED  = algn(OFF_DSUM + (size_t)TNH*TBH*TT*4);  // ~203 MB

// ---------------- helpers ----------------
DEVI int dupc(uint32_t x){
  return (int)((x & 0xffu) == 0) + (int)(((x >> 8) & 0xffu) == 0)
       + (int)(((x >> 16) & 0xffu) == 0) + (int)((x >> 24) == 0);
}
DEVI float lndup(int d){
  return d == 1 ? 0.f : d == 2 ? 0.69314718f : d == 3 ? 1.09861229f : 1.38629436f;
}
DEVI float rcpdup(int d){
  return d == 1 ? 1.f : d == 2 ? 0.5f : d == 3 ? 0.333333343f : 0.25f;
}

// dot of lane's 32-float q-half with 32 fp32 values in LDS
DEVI float dot32f(const float* kr, const float4* q4){
  const float4* k4 = (const float4*)kr;
  float4 acc = make_float4(0.f,0.f,0.f,0.f);
  #pragma unroll
  for(int x = 0; x < 8; x++){
    float4 kv = k4[x], qv = q4[x];
    acc.x = fmaf(qv.x,kv.x,acc.x); acc.y = fmaf(qv.y,kv.y,acc.y);
    acc.z = fmaf(qv.z,kv.z,acc.z); acc.w = fmaf(qv.w,kv.w,acc.w);
  }
  return (acc.x + acc.y) + (acc.z + acc.w);
}

// ---------------- K1: row sumsq (f32+f64) + per-bh max (XBOX+ ext) ----------------
__global__ void k_norms(const float* __restrict__ q, const float* __restrict__ kk,
                        float* __restrict__ qn2f, float* __restrict__ kn2f,
                        double* __restrict__ qn2d, double* __restrict__ kn2d,
                        double* __restrict__ mqk2){
  __shared__ double red[256];
  int bh = blockIdx.x, tid = threadIdx.x;
  int b = bh >> 3, hh = bh & 7;
  double mq = -1e300, mk = -1e300;
  for(int t = tid; t < TT; t += 256){
    const float4* r = (const float4*)(q + (((size_t)(b*TT + t)*TH) + hh)*TE);
    double s = 0.0;
    #pragma unroll
    for(int x = 0; x < 16; x++){
      float4 vv = r[x];
      s += (double)vv.x*vv.x + (double)vv.y*vv.y + (double)vv.z*vv.z + (double)vv.w*vv.w;
    }
    qn2d[bh*TT + t] = s; qn2f[bh*TT + t] = (float)s; mq = fmax(mq, s);
    const float4* r2 = (const float4*)(kk + (((size_t)(b*TT + t)*TH) + hh)*TE);
    double s2 = 0.0;
    #pragma unroll
    for(int x = 0; x < 16; x++){
      float4 vv = r2[x];
      s2 += (double)vv.x*vv.x + (double)vv.y*vv.y + (double)vv.z*vv.z + (double)vv.w*vv.w;
    }
    kn2d[bh*TT + t] = s2; kn2f[bh*TT + t] = (float)s2; mk = fmax(mk, s2);
  }
  red[tid] = mq; __syncthreads();
  for(int o = 128; o > 0; o >>= 1){ if(tid < o) red[tid] = fmax(red[tid], red[tid+o]); __syncthreads(); }
  double MQ = red[0]; __syncthreads();
  red[tid] = mk; __syncthreads();
  for(int o = 128; o > 0; o >>= 1){ if(tid < o) red[tid] = fmax(red[tid], red[tid+o]); __syncthreads(); }
  if(tid == 0) mqk2[bh] = MQ + red[0];   // MQ^2 + MK^2 (sumsq maxes)
}

// ---------------- K2: E2LSH hashes (float64) ----------------
__global__ void k_hash(const float* __restrict__ q, const float* __restrict__ kk,
                       const float* __restrict__ alpha, const float* __restrict__ beta,
                       const double* __restrict__ qn2d, const double* __restrict__ kn2d,
                       const double* __restrict__ mqk2,
                       double* __restrict__ qh, double* __restrict__ kh){
  __shared__ double al[264];
  __shared__ double be[4];
  int tid = threadIdx.x;
  for(int i = tid; i < 264; i += 256) al[i] = (double)alpha[i];
  if(tid < 4) be[tid] = (double)beta[tid];
  __syncthreads();
  int gid = blockIdx.x*256 + tid;
  int side = gid >> 16; int r = gid & 65535;
  int bh = r >> 12, t = r & 4095;
  int b = bh >> 3, hh = bh & 7;
  const float* x = (side ? kk : q) + (((size_t)(b*TT + t)*TH) + hh)*TE;
  const float4* xr = (const float4*)x;
  double a0 = 0.0, a1 = 0.0, a2 = 0.0, a3 = 0.0;
  #pragma unroll
  for(int c = 0; c < 16; c++){
    float4 vv = xr[c];
    const double* a = al + c*16;
    a0 += (double)vv.x*a[0]  + (double)vv.y*a[4]  + (double)vv.z*a[8]  + (double)vv.w*a[12];
    a1 += (double)vv.x*a[1]  + (double)vv.y*a[5]  + (double)vv.z*a[9]  + (double)vv.w*a[13];
    a2 += (double)vv.x*a[2]  + (double)vv.y*a[6]  + (double)vv.z*a[10] + (double)vv.w*a[14];
    a3 += (double)vv.x*a[3]  + (double)vv.y*a[7]  + (double)vv.z*a[11] + (double)vv.w*a[15];
  }
  double n2  = (side ? kn2d : qn2d)[bh*TT + t];
  double ext = sqrt(fmax(mqk2[bh] - n2, 0.0));
  int ec = side ? 65 : 64;
  double* dst = side ? kh : qh;
  dst[((size_t)0*TBH + bh)*TT + t] = a0 + ext*al[ec*4 + 0] + be[0];
  dst[((size_t)1*TBH + bh)*TT + t] = a1 + ext*al[ec*4 + 1] + be[1];
  dst[((size_t)2*TBH + bh)*TT + t] = a2 + ext*al[ec*4 + 2] + be[2];
  dst[((size_t)3*TBH + bh)*TT + t] = a3 + ext*al[ec*4 + 3] + be[3];
}

// ---------------- K3: stable argsort via bitonic on doubles ----------------
__global__ void k_sort(const double* __restrict__ qh, const double* __restrict__ kh,
                       int* __restrict__ qpos, int* __restrict__ kpos,
                       int* __restrict__ qrev, int* __restrict__ krev){
  __shared__ double v[4096];
  __shared__ int    ix[4096];
  int blk = blockIdx.x; int side = blk >> 6; int hb = blk & 63;
  const double* src = (side ? kh : qh) + (size_t)hb*TT;
  int tid = threadIdx.x;
  for(int i = tid; i < 4096; i += 256){ v[i] = src[i]; ix[i] = i; }
  __syncthreads();
  for(int k = 2; k <= 4096; k <<= 1){
    for(int j = k >> 1; j > 0; j >>= 1){
      for(int i = tid; i < 4096; i += 256){
        int l = i ^ j;
        if(l > i){
          double va = v[i], vb = v[l]; int ia = ix[i], ib = ix[l];
          bool gt  = (va > vb) || (va == vb && ia > ib);
          bool asc = ((i & k) == 0);
          if(gt == asc){ v[i] = vb; v[l] = va; ix[i] = ib; ix[l] = ia; }
        }
      }
      __syncthreads();
    }
  }
  int* pos = (side ? kpos : qpos) + (size_t)hb*TT;
  int* rev = (side ? krev : qrev) + (size_t)hb*TT;
  for(int i = tid; i < 4096; i += 256){ int id = ix[i]; pos[i] = id; rev[id] = i; }
}

// ---------------- K4a: per-bh max of key logv (stabilizer) ----------------
__global__ void k_kmax(const float* __restrict__ kk, const float* __restrict__ proj,
                       const float* __restrict__ kn2f, float* __restrict__ klsp){
  __shared__ float pj[64*256];   // pjT[e][m], 64KB
  int tid = threadIdx.x;
  int bx = blockIdx.x; int chunk = bx & 31; int bh = bx >> 5;
  for(int idx = tid; idx < 16384; idx += 256){ int e = idx >> 8, m = idx & 255; pj[idx] = proj[m*64 + e]; }
  __syncthreads();
  int b = bh >> 3, hh = bh & 7;
  int wid = tid >> 6, lane = tid & 63;
  int t0 = chunk*128;
  const float4* pj4 = (const float4*)pj;
  float mx = -1e30f;
  for(int r = wid; r < 128; r += 4){
    int t = t0 + r;
    const float4* xr = (const float4*)(kk + (((size_t)(b*TT + t)*TH) + hh)*TE);
    float4 acc = make_float4(0.f,0.f,0.f,0.f);
    #pragma unroll
    for(int c = 0; c < 16; c++){
      float4 vv = xr[c];
      const float4* p0 = pj4 + (size_t)(c*4)*64 + lane;
      float4 p;
      p = p0[0];     acc.x = fmaf(vv.x,p.x,acc.x); acc.y = fmaf(vv.x,p.y,acc.y); acc.z = fmaf(vv.x,p.z,acc.z); acc.w = fmaf(vv.x,p.w,acc.w);
      p = p0[64];    acc.x = fmaf(vv.y,p.x,acc.x); acc.y = fmaf(vv.y,p.y,acc.y); acc.z = fmaf(vv.y,p.z,acc.z); acc.w = fmaf(vv.y,p.w,acc.w);
      p = p0[128];   acc.x = fmaf(vv.z,p.x,acc.x); acc.y = fmaf(vv.z,p.y,acc.y); acc.z = fmaf(vv.z,p.z,acc.z); acc.w = fmaf(vv.z,p.w,acc.w);
      p = p0[192];   acc.x = fmaf(vv.w,p.x,acc.x); acc.y = fmaf(vv.w,p.y,acc.y); acc.z = fmaf(vv.w,p.z,acc.z); acc.w = fmaf(vv.w,p.w,acc.w);
    }
    float diag = 0.5f*C_TEMP*kn2f[bh*TT + t];
    float mr = fmaxf(fmaxf(acc.x, acc.y), fmaxf(acc.z, acc.w));
    mx = fmaxf(mx, C_DN*mr - diag);
  }
  #pragma unroll
  for(int o = 32; o > 0; o >>= 1) mx = fmaxf(mx, __shfl_xor(mx, o, 64));
  if(lane == 0) klsp[bh*128 + chunk*4 + wid] = mx;
}

__global__ void k_klsred(const float* __restrict__ klsp, float* __restrict__ kls){
  __shared__ float red[2];
  int bh = blockIdx.x, tid = threadIdx.x;
  float v = klsp[bh*128 + tid];
  #pragma unroll
  for(int o = 32; o > 0; o >>= 1) v = fmaxf(v, __shfl_xor(v, o, 64));
  if((tid & 63) == 0) red[tid >> 6] = v;
  __syncthreads();
  if(tid == 0) kls[bh] = fmaxf(red[0], red[1]);
}

// ---------------- K4c: performer features (fp32 out) ----------------
__global__ void k_feat(const float* __restrict__ q, const float* __restrict__ kk,
                       const float* __restrict__ proj, const float* __restrict__ qn2f,
                       const float* __restrict__ kn2f, const float* __restrict__ kls,
                       float* __restrict__ qp, float* __restrict__ kp,
                       float* __restrict__ pls){
  __shared__ float pj[64*256];   // pjT[e][m], 64KB
  int tid = threadIdx.x;
  int bx = blockIdx.x; int chunk = bx & 31; int bh = (bx >> 5) & 15; int side = bx >> 9;
  for(int idx = tid; idx < 16384; idx += 256){ int e = idx >> 8, m = idx & 255; pj[idx] = proj[m*64 + e]; }
  __syncthreads();
  int b = bh >> 3, hh = bh & 7;
  int wid = tid >> 6, lane = tid & 63;
  int t0 = chunk*128;
  const float* x   = side ? kk  : q;
  const float* n2a = side ? kn2f : qn2f;
  float klsv = kls[bh];
  const float4* pj4 = (const float4*)pj;
  for(int r = wid; r < 128; r += 4){
    int t = t0 + r;
    const float4* xr = (const float4*)(x + (((size_t)(b*TT + t)*TH) + hh)*TE);
    float4 acc = make_float4(0.f,0.f,0.f,0.f);
    #pragma unroll
    for(int c = 0; c < 16; c++){
      float4 vv = xr[c];
      const float4* p0 = pj4 + (size_t)(c*4)*64 + lane;
      float4 p;
      p = p0[0];     acc.x = fmaf(vv.x,p.x,acc.x); acc.y = fmaf(vv.x,p.y,acc.y); acc.z = fmaf(vv.x,p.z,acc.z); acc.w = fmaf(vv.x,p.w,acc.w);
      p = p0[64];    acc.x = fmaf(vv.y,p.x,acc.x); acc.y = fmaf(vv.y,p.y,acc.y); acc.z = fmaf(vv.y,p.z,acc.z); acc.w = fmaf(vv.y,p.w,acc.w);
      p = p0[128];   acc.x = fmaf(vv.z,p.x,acc.x); acc.y = fmaf(vv.z,p.y,acc.y); acc.z = fmaf(vv.z,p.z,acc.z); acc.w = fmaf(vv.z,p.w,acc.w);
      p = p0[192];   acc.x = fmaf(vv.w,p.x,acc.x); acc.y = fmaf(vv.w,p.y,acc.y); acc.z = fmaf(vv.w,p.z,acc.z); acc.w = fmaf(vv.w,p.w,acc.w);
    }
    float diag = 0.5f*C_TEMP*n2a[bh*TT + t];
    float d0 = fmaf(C_DN, acc.x, -diag), d1 = fmaf(C_DN, acc.y, -diag);
    float d2 = fmaf(C_DN, acc.z, -diag), d3 = fmaf(C_DN, acc.w, -diag);
    float stab;
    if(side == 0){
      float mr = fmaxf(fmaxf(d0, d1), fmaxf(d2, d3));
      #pragma unroll
      for(int o = 32; o > 0; o >>= 1) mr = fmaxf(mr, __shfl_xor(mr, o, 64));
      stab = mr;
      if(lane == 0) pls[bh*TT + t] = stab + klsv;   // prime_log_scale
    } else stab = klsv;
    float4 res = make_float4(__expf(d0 - stab)*C_RATIO, __expf(d1 - stab)*C_RATIO,
                             __expf(d2 - stab)*C_RATIO, __expf(d3 - stab)*C_RATIO);
    float* dstp = (side ? kp : qp) + ((size_t)bh*TT + t)*256 + lane*4;
    *((float4*)dstp) = res;
  }
}

// ---------------- K5: kv = k'^T v, ksum = sum_s k' ----------------
__global__ void k_kv(const float* __restrict__ kp, const float* __restrict__ v,
                     float* __restrict__ kv, float* __restrict__ ksum){
  int bx = blockIdx.x; int mt = bx & 15; int bh = bx >> 4;
  int tid = threadIdx.x; int g = tid >> 6, d = tid & 63;
  int b = bh >> 3, hh = bh & 7; int m0 = mt*16;
  float a0 = 0.f, a1 = 0.f, a2 = 0.f, a3 = 0.f;
  float s0 = 0.f, s1 = 0.f, s2 = 0.f, s3 = 0.f;
  const float* kpb = kp + (size_t)bh*TT*256 + m0 + g;
  const float* vb  = v + (size_t)b*TT*TH*TE + hh*TE + d;
  #pragma unroll 4
  for(int s = 0; s < TT; s++){
    float vv = vb[(size_t)s*512];
    const float* kr = kpb + (size_t)s*256;
    float k0 = kr[0], k1 = kr[4], k2 = kr[8], k3 = kr[12];
    a0 = fmaf(k0, vv, a0); a1 = fmaf(k1, vv, a1); a2 = fmaf(k2, vv, a2); a3 = fmaf(k3, vv, a3);
    s0 += k0; s1 += k1; s2 += k2; s3 += k3;
  }
  int m = m0 + g;
  kv[((size_t)bh*256 + m     )*64 + d] = a0;
  kv[((size_t)bh*256 + m +  4)*64 + d] = a1;
  kv[((size_t)bh*256 + m +  8)*64 + d] = a2;
  kv[((size_t)bh*256 + m + 12)*64 + d] = a3;
  if(d == 0){
    ksum[bh*256 + m] = s0; ksum[bh*256 + m + 4] = s1;
    ksum[bh*256 + m + 8] = s2; ksum[bh*256 + m + 12] = s3;
  }
}

// ---------------- K6: per-bucket attention (all fp32) ----------------
__launch_bounds__(256, 2)
__global__ void k_bucket(const float* __restrict__ q, const float* __restrict__ kk, const float* __restrict__ v,
                         const float* __restrict__ qp, const float* __restrict__ kp,
                         const int* __restrict__ qpos, const int* __restrict__ kpos,
                         const int* __restrict__ qrev, const int* __restrict__ krev,
                         const float* __restrict__ pls,
                         float* __restrict__ o_t, float* __restrict__ lse_t, float* __restrict__ dsum_t){
  __shared__ float k_l[128*64];   // fp32 keys, 32KB
  __shared__ float v_l[128*64];   // fp32 values, 32KB
  __shared__ float kp_l[8*256];   // fp32 key-features tile, 8KB
  __shared__ int   kidx[128];
  __shared__ int   kbp[128];
  int tid = threadIdx.x;
  int bx = blockIdx.x; int n = bx & 31, bh = (bx >> 5) & 15, h = bx >> 9;
  int b = bh >> 3, hh = bh & 7;

  if(tid < 128){
    int tk = kpos[((size_t)h*TBH + bh)*TT + n*128 + tid];
    kidx[tid] = tk;
    int pk = 0;
    #pragma unroll
    for(int h3 = 0; h3 < 4; h3++){ int rv = krev[((size_t)h3*TBH + bh)*TT + tk]; pk |= (rv >> 7) << (8*h3); }
    kbp[tid] = pk;
  }
  __syncthreads();
  {
    int c = tid & 15, r0 = tid >> 4;
    for(int r = r0; r < 128; r += 16){
      int tk = kidx[r];
      const float4* sk = (const float4*)(kk + (((size_t)(b*TT + tk)*TH) + hh)*TE);
      const float4* sv = (const float4*)(v  + (((size_t)(b*TT + tk)*TH) + hh)*TE);
      *((float4*)(k_l + r*64 + c*4)) = sk[c];
      *((float4*)(v_l + r*64 + c*4)) = sv[c];
    }
  }

  int i  = tid >> 1, h2 = tid & 1;
  int slot = n*128 + i;
  int tq = qpos[((size_t)h*TBH + bh)*TT + slot];
  float4 q4[8];
  { const float4* qs = (const float4*)(q + (((size_t)(b*TT + tq)*TH) + hh)*TE + h2*32);
    #pragma unroll
    for(int x = 0; x < 8; x++) q4[x] = qs[x]; }
  float4 qp4[32];
  { const float4* ps = (const float4*)(qp + ((size_t)bh*TT + tq)*256 + h2*128);
    #pragma unroll
    for(int x = 0; x < 32; x++) qp4[x] = ps[x]; }
  float plsv = pls[(size_t)bh*TT + tq];
  int qbp = 0;
  #pragma unroll
  for(int h3 = 0; h3 < 4; h3++){ int rv = qrev[((size_t)h3*TBH + bh)*TT + tq]; qbp |= (rv >> 7) << (8*h3); }
  __syncthreads();

  // phase 1: row max (lse)
  float lse = plsv;
  #pragma unroll 2
  for(int j = 0; j < 128; j++){
    float s = dot32f(k_l + j*64 + h2*32, q4);
    s += __shfl_xor(s, 1, 64);
    int du = dupc((uint32_t)(qbp ^ kbp[j]));
    float inr = fmaf(C_TEMP, s, -lndup(du));
    lse = fmaxf(lse, inr);
  }

  // phase 2: dots = exp(inner - lse) - dp*exp(pls - lse), accumulate PV
  float pfac = __expf(plsv - lse);
  float dsum = 0.f;
  float4 so[8];
  #pragma unroll
  for(int x = 0; x < 8; x++) so[x] = make_float4(0.f,0.f,0.f,0.f);
  for(int jt = 0; jt < 16; jt++){
    __syncthreads();
    { int jj = tid >> 5, c = tid & 31;
      int tk = kidx[jt*8 + jj];
      const float4* src = (const float4*)(kp + ((size_t)bh*TT + tk)*256);
      float4 u0 = src[c*2], u1 = src[c*2 + 1];
      float4* dst = (float4*)(kp_l + jj*256 + c*8);
      dst[0] = u0; dst[1] = u1;
    }
    __syncthreads();
    #pragma unroll 2
    for(int jj = 0; jj < 8; jj++){
      int j = jt*8 + jj;
      float s = dot32f(k_l + j*64 + h2*32, q4);
      s += __shfl_xor(s, 1, 64);
      float4 pa = make_float4(0.f,0.f,0.f,0.f);
      const float4* prr = (const float4*)(kp_l + jj*256 + h2*128);
      #pragma unroll
      for(int x = 0; x < 32; x++){
        float4 pv = prr[x];
        pa.x = fmaf(qp4[x].x, pv.x, pa.x); pa.y = fmaf(qp4[x].y, pv.y, pa.y);
        pa.z = fmaf(qp4[x].z, pv.z, pa.z); pa.w = fmaf(qp4[x].w, pv.w, pa.w);
      }
      float dp = (pa.x + pa.y) + (pa.z + pa.w);
      dp += __shfl_xor(dp, 1, 64);
      int du = dupc((uint32_t)(qbp ^ kbp[j]));
      float ein  = __expf(fmaf(C_TEMP, s, -lndup(du)) - lse);
      float dots = fmaf(-dp*rcpdup(du), pfac, ein);
      dsum += dots;
      const float4* vr = (const float4*)(v_l + j*64 + h2*32);
      #pragma unroll
      for(int x = 0; x < 8; x++){
        float4 vA = vr[x];
        so[x].x = fmaf(dots, vA.x, so[x].x); so[x].y = fmaf(dots, vA.y, so[x].y);
        so[x].z = fmaf(dots, vA.z, so[x].z); so[x].w = fmaf(dots, vA.w, so[x].w);
      }
    }
  }
  size_t ob = ((((size_t)h*TBH + bh)*TT) + tq)*64 + h2*32;
  float4* od = (float4*)(o_t + ob);
  #pragma unroll
  for(int x = 0; x < 8; x++) od[x] = so[x];
  if(h2 == 0){
    lse_t [((size_t)h*TBH + bh)*TT + tq] = lse;
    dsum_t[((size_t)h*TBH + bh)*TT + tq] = dsum;
  }
}

// ---------------- K7: combine hash rounds + performer term ----------------
__global__ void k_final(const float* __restrict__ qp, const float* __restrict__ kv,
                        const float* __restrict__ ksum, const float* __restrict__ o_t,
                        const float* __restrict__ lse_t, const float* __restrict__ dsum_t,
                        const float* __restrict__ pls, float* __restrict__ out){
  __shared__ float kv_l[256*64];   // fp32-staged kv, 64KB
  int tid = threadIdx.x;
  int bx = blockIdx.x; int chunk = bx & 15; int bh = bx >> 4;
  for(int idx = tid; idx < 16384; idx += 256) kv_l[idx] = kv[(size_t)bh*16384 + idx];
  __syncthreads();
  int wid = tid >> 6, lane = tid & 63;
  int b = bh >> 3, hh = bh & 7;
  int t0 = chunk*256;
  for(int r = wid; r < 256; r += 4){
    int t = t0 + r;
    const float* qr = qp + ((size_t)bh*TT + t)*256;
    float q0 = qr[lane], q1 = qr[64 + lane], q2 = qr[128 + lane], q3 = qr[192 + lane];
    float qkv = 0.f;
    #pragma unroll 8
    for(int mm = 0; mm < 64; mm++){
      float c0 = __shfl(q0, mm, 64), c1 = __shfl(q1, mm, 64), c2 = __shfl(q2, mm, 64), c3 = __shfl(q3, mm, 64);
      qkv = fmaf(c0, kv_l[(      mm)*64 + lane], qkv);
      qkv = fmaf(c1, kv_l[( 64 + mm)*64 + lane], qkv);
      qkv = fmaf(c2, kv_l[(128 + mm)*64 + lane], qkv);
      qkv = fmaf(c3, kv_l[(192 + mm)*64 + lane], qkv);
    }
    float p1 = q0*ksum[bh*256 + lane] + q1*ksum[bh*256 + 64 + lane]
             + q2*ksum[bh*256 + 128 + lane] + q3*ksum[bh*256 + 192 + lane];
    #pragma unroll
    for(int o = 32; o > 0; o >>= 1) p1 += __shfl_xor(p1, o, 64);
    float l0 = lse_t[((size_t)0*TBH + bh)*TT + t], l1 = lse_t[((size_t)1*TBH + bh)*TT + t];
    float l2 = lse_t[((size_t)2*TBH + bh)*TT + t], l3 = lse_t[((size_t)3*TBH + bh)*TT + t];
    float M = fmaxf(fmaxf(l0, l1), fmaxf(l2, l3));
    float e0 = __expf(l0 - M), e1 = __expf(l1 - M), e2 = __expf(l2 - M), e3 = __expf(l3 - M);
    float rs = 1.f / (e0 + e1 + e2 + e3);
    float pr0 = e0*rs, pr1 = e1*rs, pr2 = e2*rs, pr3 = e3*rs;
    float psc = __expf(pls[bh*TT + t] - M)*rs;
    float outl = 0.f, nrm = 0.f;
    outl = fmaf(o_t[(((size_t)0*TBH + bh)*TT + t)*64 + lane], pr0, outl);
    outl = fmaf(o_t[(((size_t)1*TBH + bh)*TT + t)*64 + lane], pr1, outl);
    outl = fmaf(o_t[(((size_t)2*TBH + bh)*TT + t)*64 + lane], pr2, outl);
    outl = fmaf(o_t[(((size_t)3*TBH + bh)*TT + t)*64 + lane], pr3, outl);
    nrm  = fmaf(dsum_t[((size_t)0*TBH + bh)*TT + t], pr0, nrm);
    nrm  = fmaf(dsum_t[((size_t)1*TBH + bh)*TT + t], pr1, nrm);
    nrm  = fmaf(dsum_t[((size_t)2*TBH + bh)*TT + t], pr2, nrm);
    nrm  = fmaf(dsum_t[((size_t)3*TBH + bh)*TT + t], pr3, nrm);
    nrm  = fmaf(p1, psc, nrm);
    float res = (outl + qkv*psc) / fmaxf(nrm, 1e-6f);
    out[((size_t)(b*TT + t)*TH + hh)*64 + lane] = res;
  }
}

// sentinel: signals ws_size-too-small distinctly from a numeric bug
__global__ void k_sentinel(float* __restrict__ out, int n){
  int i = blockIdx.x*256 + threadIdx.x;
  if(i < n) out[i] = 12345.0f;
}

extern "C" void kernel_launch(void* const* d_in, const int* in_sizes, int n_in,
                              void* d_out, int out_size, void* d_ws, size_t ws_size,
                              hipStream_t stream){
  const float* q     = (const float*)d_in[0];
  const float* k     = (const float*)d_in[1];
  const float* v     = (const float*)d_in[2];
  const float* proj  = (const float*)d_in[3];
  const float* alpha = (const float*)d_in[4];
  const float* beta  = (const float*)d_in[5];
  float* out = (float*)d_out;
  char* ws = (char*)d_ws;

  if(ws_size < WS_NEED){
    k_sentinel<<<dim3((out_size + 255)/256), dim3(256), 0, stream>>>(out, out_size);
    return;
  }

  float*  qn2f  = (float*) (ws + OFF_QN2F);
  float*  kn2f  = (float*) (ws + OFF_KN2F);
  double* qn2d  = (double*)(ws + OFF_QN2D);
  double* kn2d  = (double*)(ws + OFF_KN2D);
  double* mqk2  = (double*)(ws + OFF_MQK2);
  double* qh    = (double*)(ws + OFF_QH);
  double* kh    = (double*)(ws + OFF_KH);
  int*   qpos   = (int*)  (ws + OFF_QPOS);
  int*   kpos   = (int*)  (ws + OFF_KPOS);
  int*   qrev   = (int*)  (ws + OFF_QREV);
  int*   krev   = (int*)  (ws + OFF_KREV);
  float* klsp   = (float*)(ws + OFF_KLSP);
  float* kls    = (float*)(ws + OFF_KLS);
  float* qp     = (float*)(ws + OFF_QP);
  float* kp     = (float*)(ws + OFF_KP);
  float* pls    = (float*)(ws + OFF_PLS);
  float* ksum   = (float*)(ws + OFF_KSUM);
  float* kvv    = (float*)(ws + OFF_KV);
  float* o_t    = (float*)(ws + OFF_OT);
  float* lse_t  = (float*)(ws + OFF_LSET);
  float* dsum_t = (float*)(ws + OFF_DSUM);

  k_norms <<<dim3(16),   dim3(256), 0, stream>>>(q, k, qn2f, kn2f, qn2d, kn2d, mqk2);
  k_hash  <<<dim3(512),  dim3(256), 0, stream>>>(q, k, alpha, beta, qn2d, kn2d, mqk2, qh, kh);
  k_sort  <<<dim3(128),  dim3(256), 0, stream>>>(qh, kh, qpos, kpos, qrev, krev);
  k_kmax  <<<dim3(512),  dim3(256), 0, stream>>>(k, proj, kn2f, klsp);
  k_klsred<<<dim3(16),   dim3(128), 0, stream>>>(klsp, kls);
  k_feat  <<<dim3(1024), dim3(256), 0, stream>>>(q, k, proj, qn2f, kn2f, kls, qp, kp, pls);
  k_kv    <<<dim3(256),  dim3(256), 0, stream>>>(kp, v, kvv, ksum);
  k_bucket<<<dim3(2048), dim3(256), 0, stream>>>(q, k, v, qp, kp, qpos, kpos, qrev, krev, pls, o_t, lse_t, dsum_t);
  k_final <<<dim3(256),  dim3(256), 0, stream>>>(qp, kvv, ksum, o_t, lse_t, dsum_t, pls, out);
}

// Round 3
// 3996.813 us; speedup vs baseline: 1.1588x; 1.1588x over previous
//
#include <hip/hip_runtime.h>
#include <stdint.h>
#include <math.h>

#define DEVI __device__ __forceinline__

// Problem constants (B,T,H,E fixed by the reference setup)
constexpr int TB  = 2;
constexpr int TT  = 4096;
constexpr int TH  = 8;
constexpr int TE  = 64;
constexpr int TBH = 16;   // B*H
constexpr int TM  = 256;  // performer features
constexpr int TNH = 4;    // hash rounds
constexpr float C_TEMP  = 0.125f;                 // 1/sqrt(E)
constexpr float C_DN    = 0.35355339059327373f;   // sqrt(temp)
constexpr float C_RATIO = 0.0625f;                // M^-0.5

// ---------------- workspace layout ----------------
constexpr size_t algn(size_t x){ return (x + 255) & ~(size_t)255; }
constexpr size_t OFF_QN2F = 0;
constexpr size_t OFF_KN2F = algn(OFF_QN2F + (size_t)TBH*TT*4);
constexpr size_t OFF_QN2D = algn(OFF_KN2F + (size_t)TBH*TT*4);
constexpr size_t OFF_KN2D = algn(OFF_QN2D + (size_t)TBH*TT*8);
constexpr size_t OFF_MQK2 = algn(OFF_KN2D + (size_t)TBH*TT*8);
constexpr size_t OFF_QMAXP= algn(OFF_MQK2 + (size_t)TBH*8);
constexpr size_t OFF_KMAXP= algn(OFF_QMAXP+ (size_t)TBH*16*8);
constexpr size_t OFF_QH   = algn(OFF_KMAXP+ (size_t)TBH*16*8);
constexpr size_t OFF_KH   = algn(OFF_QH   + (size_t)TNH*TBH*TT*8);
constexpr size_t OFF_QPOS = algn(OFF_KH   + (size_t)TNH*TBH*TT*8);
constexpr size_t OFF_KPOS = algn(OFF_QPOS + (size_t)TNH*TBH*TT*4);
constexpr size_t OFF_QREV = algn(OFF_KPOS + (size_t)TNH*TBH*TT*4);
constexpr size_t OFF_KREV = algn(OFF_QREV + (size_t)TNH*TBH*TT*4);
constexpr size_t OFF_KLSP = algn(OFF_KREV + (size_t)TNH*TBH*TT*4);
constexpr size_t OFF_KLS  = algn(OFF_KLSP + (size_t)TBH*128*4);
constexpr size_t OFF_QP   = algn(OFF_KLS  + (size_t)TBH*4);
constexpr size_t OFF_KP   = algn(OFF_QP   + (size_t)TBH*TT*TM*4);   // fp32
constexpr size_t OFF_PLS  = algn(OFF_KP   + (size_t)TBH*TT*TM*4);   // fp32 (q-rowmax only; add kls downstream)
constexpr size_t OFF_KSUM = algn(OFF_PLS  + (size_t)TBH*TT*4);
constexpr size_t OFF_KV   = algn(OFF_KSUM + (size_t)TBH*TM*4);
constexpr size_t OFF_OT   = algn(OFF_KV   + (size_t)TBH*TM*TE*4);
constexpr size_t OFF_LSET = algn(OFF_OT   + (size_t)TNH*TBH*TT*TE*4);
constexpr size_t OFF_DSUM = algn(OFF_LSET + (size_t)TNH*TBH*TT*4);
constexpr size_t WS_NEED  = algn(OFF_DSUM + (size_t)TNH*TBH*TT*4);  // ~203 MB

// ---------------- helpers ----------------
DEVI int dupc(uint32_t x){
  return (int)((x & 0xffu) == 0) + (int)(((x >> 8) & 0xffu) == 0)
       + (int)(((x >> 16) & 0xffu) == 0) + (int)((x >> 24) == 0);
}
DEVI float lndup(int d){
  return d == 1 ? 0.f : d == 2 ? 0.69314718f : d == 3 ? 1.09861229f : 1.38629436f;
}
DEVI float rcpdup(int d){
  return d == 1 ? 1.f : d == 2 ? 0.5f : d == 3 ? 0.333333343f : 0.25f;
}

// dot of lane's 32-float q-half with 32 fp32 values in LDS
DEVI float dot32f(const float* kr, const float4* q4){
  const float4* k4 = (const float4*)kr;
  float4 acc = make_float4(0.f,0.f,0.f,0.f);
  #pragma unroll
  for(int x = 0; x < 8; x++){
    float4 kv = k4[x], qv = q4[x];
    acc.x = fmaf(qv.x,kv.x,acc.x); acc.y = fmaf(qv.y,kv.y,acc.y);
    acc.z = fmaf(qv.z,kv.z,acc.z); acc.w = fmaf(qv.w,kv.w,acc.w);
  }
  return (acc.x + acc.y) + (acc.z + acc.w);
}

// ---------------- K1: row sumsq (f32+f64) + partial max (XBOX+ ext) ----------------
__global__ void k_norms2(const float* __restrict__ q, const float* __restrict__ kk,
                         float* __restrict__ qn2f, float* __restrict__ kn2f,
                         double* __restrict__ qn2d, double* __restrict__ kn2d,
                         double* __restrict__ qmaxp, double* __restrict__ kmaxp){
  __shared__ double red[256];
  int bx = blockIdx.x; int chunk = bx & 15, bh = bx >> 4;
  int tid = threadIdx.x;
  int b = bh >> 3, hh = bh & 7;
  int t = chunk*256 + tid;
  const float4* r1 = (const float4*)(q + (((size_t)(b*TT + t)*TH) + hh)*TE);
  double s = 0.0;
  #pragma unroll
  for(int x = 0; x < 16; x++){
    float4 vv = r1[x];
    s += (double)vv.x*vv.x + (double)vv.y*vv.y + (double)vv.z*vv.z + (double)vv.w*vv.w;
  }
  qn2d[bh*TT + t] = s; qn2f[bh*TT + t] = (float)s;
  const float4* r2 = (const float4*)(kk + (((size_t)(b*TT + t)*TH) + hh)*TE);
  double s2 = 0.0;
  #pragma unroll
  for(int x = 0; x < 16; x++){
    float4 vv = r2[x];
    s2 += (double)vv.x*vv.x + (double)vv.y*vv.y + (double)vv.z*vv.z + (double)vv.w*vv.w;
  }
  kn2d[bh*TT + t] = s2; kn2f[bh*TT + t] = (float)s2;
  red[tid] = s; __syncthreads();
  for(int o = 128; o > 0; o >>= 1){ if(tid < o) red[tid] = fmax(red[tid], red[tid+o]); __syncthreads(); }
  if(tid == 0) qmaxp[bh*16 + chunk] = red[0];
  __syncthreads();
  red[tid] = s2; __syncthreads();
  for(int o = 128; o > 0; o >>= 1){ if(tid < o) red[tid] = fmax(red[tid], red[tid+o]); __syncthreads(); }
  if(tid == 0) kmaxp[bh*16 + chunk] = red[0];
}

__global__ void k_mqk(const double* __restrict__ qmaxp, const double* __restrict__ kmaxp,
                      double* __restrict__ mqk2){
  int bh = blockIdx.x;
  if(threadIdx.x == 0){
    double mq = -1e300, mk = -1e300;
    for(int i = 0; i < 16; i++){ mq = fmax(mq, qmaxp[bh*16 + i]); mk = fmax(mk, kmaxp[bh*16 + i]); }
    mqk2[bh] = mq + mk;
  }
}

// ---------------- K2: E2LSH hashes (float64) ----------------
__global__ void k_hash(const float* __restrict__ q, const float* __restrict__ kk,
                       const float* __restrict__ alpha, const float* __restrict__ beta,
                       const double* __restrict__ qn2d, const double* __restrict__ kn2d,
                       const double* __restrict__ mqk2,
                       double* __restrict__ qh, double* __restrict__ kh){
  __shared__ double al[264];
  __shared__ double be[4];
  int tid = threadIdx.x;
  for(int i = tid; i < 264; i += 256) al[i] = (double)alpha[i];
  if(tid < 4) be[tid] = (double)beta[tid];
  __syncthreads();
  int gid = blockIdx.x*256 + tid;
  int side = gid >> 16; int r = gid & 65535;
  int bh = r >> 12, t = r & 4095;
  int b = bh >> 3, hh = bh & 7;
  const float* x = (side ? kk : q) + (((size_t)(b*TT + t)*TH) + hh)*TE;
  const float4* xr = (const float4*)x;
  double a0 = 0.0, a1 = 0.0, a2 = 0.0, a3 = 0.0;
  #pragma unroll
  for(int c = 0; c < 16; c++){
    float4 vv = xr[c];
    const double* a = al + c*16;
    a0 += (double)vv.x*a[0]  + (double)vv.y*a[4]  + (double)vv.z*a[8]  + (double)vv.w*a[12];
    a1 += (double)vv.x*a[1]  + (double)vv.y*a[5]  + (double)vv.z*a[9]  + (double)vv.w*a[13];
    a2 += (double)vv.x*a[2]  + (double)vv.y*a[6]  + (double)vv.z*a[10] + (double)vv.w*a[14];
    a3 += (double)vv.x*a[3]  + (double)vv.y*a[7]  + (double)vv.z*a[11] + (double)vv.w*a[15];
  }
  double n2  = (side ? kn2d : qn2d)[bh*TT + t];
  double ext = sqrt(fmax(mqk2[bh] - n2, 0.0));
  int ec = side ? 65 : 64;
  double* dst = side ? kh : qh;
  dst[((size_t)0*TBH + bh)*TT + t] = a0 + ext*al[ec*4 + 0] + be[0];
  dst[((size_t)1*TBH + bh)*TT + t] = a1 + ext*al[ec*4 + 1] + be[1];
  dst[((size_t)2*TBH + bh)*TT + t] = a2 + ext*al[ec*4 + 2] + be[2];
  dst[((size_t)3*TBH + bh)*TT + t] = a3 + ext*al[ec*4 + 3] + be[3];
}

// ---------------- K3: stable argsort via bitonic on doubles ----------------
__global__ void k_sort(const double* __restrict__ qh, const double* __restrict__ kh,
                       int* __restrict__ qpos, int* __restrict__ kpos,
                       int* __restrict__ qrev, int* __restrict__ krev){
  __shared__ double v[4096];
  __shared__ int    ix[4096];
  int blk = blockIdx.x; int side = blk >> 6; int hb = blk & 63;
  const double* src = (side ? kh : qh) + (size_t)hb*TT;
  int tid = threadIdx.x;
  for(int i = tid; i < 4096; i += 256){ v[i] = src[i]; ix[i] = i; }
  __syncthreads();
  for(int k = 2; k <= 4096; k <<= 1){
    for(int j = k >> 1; j > 0; j >>= 1){
      for(int i = tid; i < 4096; i += 256){
        int l = i ^ j;
        if(l > i){
          double va = v[i], vb = v[l]; int ia = ix[i], ib = ix[l];
          bool gt  = (va > vb) || (va == vb && ia > ib);
          bool asc = ((i & k) == 0);
          if(gt == asc){ v[i] = vb; v[l] = va; ix[i] = ib; ix[l] = ia; }
        }
      }
      __syncthreads();
    }
  }
  int* pos = (side ? kpos : qpos) + (size_t)hb*TT;
  int* rev = (side ? krev : qrev) + (size_t)hb*TT;
  for(int i = tid; i < 4096; i += 256){ int id = ix[i]; pos[i] = id; rev[id] = i; }
}

// ---------------- K4: performer projection, 3 modes ----------------
// MODE 0: q-side  -> qp = exp(dash - rowmax)*ratio, pls = rowmax
// MODE 1: k-side  -> block max of dash -> pmax[bh*128+chunk]
// MODE 2: k-side  -> kp = exp(dash - kls[bh])*ratio
// Structure: proj fragments in VGPRs (one m per lane, loaded once via padded
// LDS quarter staged with coalesced global reads); x-tile (32 rows) in LDS,
// read via broadcast ds_read_b128. No scattered global access anywhere.
template<int MODE>
__launch_bounds__(256, 3)
__global__ void k_proj(const float* __restrict__ x, const float* __restrict__ proj,
                       const float* __restrict__ n2a, const float* __restrict__ kls,
                       float* __restrict__ outp, float* __restrict__ pmax,
                       float* __restrict__ pls){
  __shared__ float projL[64*68];   // one m-quarter, padded stride 68 (17.4 KB)
  __shared__ float x_l[32*64];     // 32 rows of x (8 KB)
  __shared__ float x_n[32];
  __shared__ float wred[4*32];
  int tid = threadIdx.x, wid = tid >> 6, lane = tid & 63;
  int bx = blockIdx.x; int chunk = bx & 127, bh = bx >> 7;
  int b = bh >> 3, hh = bh & 7, t0 = chunk*32;

  // stage x rows (coalesced): 8 threads/row, 2 float4 each
  {
    int r = tid >> 3, cc = tid & 7;
    const float4* src = (const float4*)(x + (((size_t)(b*TT + t0 + r)*TH) + hh)*TE);
    float4* dst = (float4*)(x_l + r*64);
    dst[cc] = src[cc]; dst[cc + 8] = src[cc + 8];
  }
  if(tid < 32) x_n[tid] = n2a[bh*TT + t0 + tid];

  // stage proj quarters (coalesced global) and load per-lane registers
  float4 pj[16];
  for(int ww = 0; ww < 4; ww++){
    __syncthreads();
    #pragma unroll
    for(int n = 0; n < 16; n++){
      int idx = n*256 + tid;
      projL[(idx >> 6)*68 + (idx & 63)] = proj[ww*4096 + idx];
    }
    __syncthreads();
    if(wid == ww){
      const float4* p4 = (const float4*)(projL + lane*68);   // 272B stride, 16B aligned
      #pragma unroll
      for(int c = 0; c < 16; c++) pj[c] = p4[c];
    }
  }
  __syncthreads();

  // dash accumulation: acc[r] over e ascending (same fmaf chain as reference path)
  float acc[32];
  #pragma unroll
  for(int r = 0; r < 32; r++) acc[r] = 0.f;
  for(int e4 = 0; e4 < 16; e4++){
    float4 pjv = pj[e4];
    #pragma unroll
    for(int r = 0; r < 32; r++){
      float4 x4 = *((const float4*)(x_l + r*64 + e4*4));   // broadcast
      float a = acc[r];
      a = fmaf(x4.x, pjv.x, a); a = fmaf(x4.y, pjv.y, a);
      a = fmaf(x4.z, pjv.z, a); a = fmaf(x4.w, pjv.w, a);
      acc[r] = a;
    }
  }
  #pragma unroll
  for(int r = 0; r < 32; r++) acc[r] = fmaf(C_DN, acc[r], -0.5f*C_TEMP*x_n[r]);

  if constexpr (MODE == 1){
    float mx = -1e30f;
    #pragma unroll
    for(int r = 0; r < 32; r++) mx = fmaxf(mx, acc[r]);
    #pragma unroll
    for(int o = 32; o > 0; o >>= 1) mx = fmaxf(mx, __shfl_xor(mx, o, 64));
    if(lane == 0) wred[wid] = mx;
    __syncthreads();
    if(tid == 0) pmax[bh*128 + chunk] = fmaxf(fmaxf(wred[0], wred[1]), fmaxf(wred[2], wred[3]));
  }
  if constexpr (MODE == 2){
    float stab = kls[bh];
    #pragma unroll
    for(int r = 0; r < 32; r++){
      outp[((size_t)bh*TT + t0 + r)*256 + wid*64 + lane] = __expf(acc[r] - stab)*C_RATIO;
    }
  }
  if constexpr (MODE == 0){
    #pragma unroll
    for(int r = 0; r < 32; r++){
      float m = acc[r];
      #pragma unroll
      for(int o = 32; o > 0; o >>= 1) m = fmaxf(m, __shfl_xor(m, o, 64));
      if(lane == 0) wred[wid*32 + r] = m;
    }
    __syncthreads();
    #pragma unroll
    for(int r = 0; r < 32; r++){
      float st = fmaxf(fmaxf(wred[r], wred[32 + r]), fmaxf(wred[64 + r], wred[96 + r]));
      outp[((size_t)bh*TT + t0 + r)*256 + wid*64 + lane] = __expf(acc[r] - st)*C_RATIO;
    }
    if(tid < 32){
      float st = fmaxf(fmaxf(wred[tid], wred[32 + tid]), fmaxf(wred[64 + tid], wred[96 + tid]));
      pls[(size_t)bh*TT + t0 + tid] = st;   // q-rowmax; kls added downstream
    }
  }
}

__global__ void k_klsred(const float* __restrict__ klsp, float* __restrict__ kls){
  __shared__ float red[2];
  int bh = blockIdx.x, tid = threadIdx.x;
  float v = klsp[bh*128 + tid];
  #pragma unroll
  for(int o = 32; o > 0; o >>= 1) v = fmaxf(v, __shfl_xor(v, o, 64));
  if((tid & 63) == 0) red[tid >> 6] = v;
  __syncthreads();
  if(tid == 0) kls[bh] = fmaxf(red[0], red[1]);
}

// ---------------- K5: kv = k'^T v, ksum = sum_s k' ----------------
__global__ void k_kv(const float* __restrict__ kp, const float* __restrict__ v,
                     float* __restrict__ kv, float* __restrict__ ksum){
  int bx = blockIdx.x; int mt = bx & 15; int bh = bx >> 4;
  int tid = threadIdx.x; int g = tid >> 6, d = tid & 63;
  int b = bh >> 3, hh = bh & 7; int m0 = mt*16;
  float a0 = 0.f, a1 = 0.f, a2 = 0.f, a3 = 0.f;
  float s0 = 0.f, s1 = 0.f, s2 = 0.f, s3 = 0.f;
  const float* kpb = kp + (size_t)bh*TT*256 + m0 + g;
  const float* vb  = v + (size_t)b*TT*TH*TE + hh*TE + d;
  #pragma unroll 4
  for(int s = 0; s < TT; s++){
    float vv = vb[(size_t)s*512];
    const float* kr = kpb + (size_t)s*256;
    float k0 = kr[0], k1 = kr[4], k2 = kr[8], k3 = kr[12];
    a0 = fmaf(k0, vv, a0); a1 = fmaf(k1, vv, a1); a2 = fmaf(k2, vv, a2); a3 = fmaf(k3, vv, a3);
    s0 += k0; s1 += k1; s2 += k2; s3 += k3;
  }
  int m = m0 + g;
  kv[((size_t)bh*256 + m     )*64 + d] = a0;
  kv[((size_t)bh*256 + m +  4)*64 + d] = a1;
  kv[((size_t)bh*256 + m +  8)*64 + d] = a2;
  kv[((size_t)bh*256 + m + 12)*64 + d] = a3;
  if(d == 0){
    ksum[bh*256 + m] = s0; ksum[bh*256 + m + 4] = s1;
    ksum[bh*256 + m + 8] = s2; ksum[bh*256 + m + 12] = s3;
  }
}

// ---------------- K6: per-bucket attention (all fp32) ----------------
__launch_bounds__(256, 2)
__global__ void k_bucket(const float* __restrict__ q, const float* __restrict__ kk, const float* __restrict__ v,
                         const float* __restrict__ qp, const float* __restrict__ kp,
                         const int* __restrict__ qpos, const int* __restrict__ kpos,
                         const int* __restrict__ qrev, const int* __restrict__ krev,
                         const float* __restrict__ pls, const float* __restrict__ kls,
                         float* __restrict__ o_t, float* __restrict__ lse_t, float* __restrict__ dsum_t){
  __shared__ float k_l[128*64];   // fp32 keys, 32KB
  __shared__ float v_l[128*64];   // fp32 values, 32KB
  __shared__ float kp_l[8*256];   // fp32 key-features tile, 8KB
  __shared__ int   kidx[128];
  __shared__ int   kbp[128];
  int tid = threadIdx.x;
  int bx = blockIdx.x; int n = bx & 31, bh = (bx >> 5) & 15, h = bx >> 9;
  int b = bh >> 3, hh = bh & 7;

  if(tid < 128){
    int tk = kpos[((size_t)h*TBH + bh)*TT + n*128 + tid];
    kidx[tid] = tk;
    int pk = 0;
    #pragma unroll
    for(int h3 = 0; h3 < 4; h3++){ int rv = krev[((size_t)h3*TBH + bh)*TT + tk]; pk |= (rv >> 7) << (8*h3); }
    kbp[tid] = pk;
  }
  __syncthreads();
  {
    int c = tid & 15, r0 = tid >> 4;
    for(int r = r0; r < 128; r += 16){
      int tk = kidx[r];
      const float4* sk = (const float4*)(kk + (((size_t)(b*TT + tk)*TH) + hh)*TE);
      const float4* sv = (const float4*)(v  + (((size_t)(b*TT + tk)*TH) + hh)*TE);
      *((float4*)(k_l + r*64 + c*4)) = sk[c];
      *((float4*)(v_l + r*64 + c*4)) = sv[c];
    }
  }

  int i  = tid >> 1, h2 = tid & 1;
  int slot = n*128 + i;
  int tq = qpos[((size_t)h*TBH + bh)*TT + slot];
  float4 q4[8];
  { const float4* qs = (const float4*)(q + (((size_t)(b*TT + tq)*TH) + hh)*TE + h2*32);
    #pragma unroll
    for(int x = 0; x < 8; x++) q4[x] = qs[x]; }
  float4 qp4[32];
  { const float4* ps = (const float4*)(qp + ((size_t)bh*TT + tq)*256 + h2*128);
    #pragma unroll
    for(int x = 0; x < 32; x++) qp4[x] = ps[x]; }
  float plsv = pls[(size_t)bh*TT + tq] + kls[bh];
  int qbp = 0;
  #pragma unroll
  for(int h3 = 0; h3 < 4; h3++){ int rv = qrev[((size_t)h3*TBH + bh)*TT + tq]; qbp |= (rv >> 7) << (8*h3); }
  __syncthreads();

  // phase 1: row max (lse)
  float lse = plsv;
  #pragma unroll 2
  for(int j = 0; j < 128; j++){
    float s = dot32f(k_l + j*64 + h2*32, q4);
    s += __shfl_xor(s, 1, 64);
    int du = dupc((uint32_t)(qbp ^ kbp[j]));
    float inr = fmaf(C_TEMP, s, -lndup(du));
    lse = fmaxf(lse, inr);
  }

  // phase 2: dots = exp(inner - lse) - dp*exp(pls - lse), accumulate PV
  float pfac = __expf(plsv - lse);
  float dsum = 0.f;
  float4 so[8];
  #pragma unroll
  for(int x = 0; x < 8; x++) so[x] = make_float4(0.f,0.f,0.f,0.f);
  for(int jt = 0; jt < 16; jt++){
    __syncthreads();
    { int jj = tid >> 5, c = tid & 31;
      int tk = kidx[jt*8 + jj];
      const float4* src = (const float4*)(kp + ((size_t)bh*TT + tk)*256);
      float4 u0 = src[c*2], u1 = src[c*2 + 1];
      float4* dst = (float4*)(kp_l + jj*256 + c*8);
      dst[0] = u0; dst[1] = u1;
    }
    __syncthreads();
    #pragma unroll 2
    for(int jj = 0; jj < 8; jj++){
      int j = jt*8 + jj;
      float s = dot32f(k_l + j*64 + h2*32, q4);
      s += __shfl_xor(s, 1, 64);
      float4 pa = make_float4(0.f,0.f,0.f,0.f);
      const float4* prr = (const float4*)(kp_l + jj*256 + h2*128);
      #pragma unroll
      for(int x = 0; x < 32; x++){
        float4 pv = prr[x];
        pa.x = fmaf(qp4[x].x, pv.x, pa.x); pa.y = fmaf(qp4[x].y, pv.y, pa.y);
        pa.z = fmaf(qp4[x].z, pv.z, pa.z); pa.w = fmaf(qp4[x].w, pv.w, pa.w);
      }
      float dp = (pa.x + pa.y) + (pa.z + pa.w);
      dp += __shfl_xor(dp, 1, 64);
      int du = dupc((uint32_t)(qbp ^ kbp[j]));
      float ein  = __expf(fmaf(C_TEMP, s, -lndup(du)) - lse);
      float dots = fmaf(-dp*rcpdup(du), pfac, ein);
      dsum += dots;
      const float4* vr = (const float4*)(v_l + j*64 + h2*32);
      #pragma unroll
      for(int x = 0; x < 8; x++){
        float4 vA = vr[x];
        so[x].x = fmaf(dots, vA.x, so[x].x); so[x].y = fmaf(dots, vA.y, so[x].y);
        so[x].z = fmaf(dots, vA.z, so[x].z); so[x].w = fmaf(dots, vA.w, so[x].w);
      }
    }
  }
  size_t ob = ((((size_t)h*TBH + bh)*TT) + tq)*64 + h2*32;
  float4* od = (float4*)(o_t + ob);
  #pragma unroll
  for(int x = 0; x < 8; x++) od[x] = so[x];
  if(h2 == 0){
    lse_t [((size_t)h*TBH + bh)*TT + tq] = lse;
    dsum_t[((size_t)h*TBH + bh)*TT + tq] = dsum;
  }
}

// ---------------- K7: combine hash rounds + performer term ----------------
__global__ void k_final(const float* __restrict__ qp, const float* __restrict__ kv,
                        const float* __restrict__ ksum, const float* __restrict__ o_t,
                        const float* __restrict__ lse_t, const float* __restrict__ dsum_t,
                        const float* __restrict__ pls, const float* __restrict__ kls,
                        float* __restrict__ out){
  __shared__ float kv_l[256*64];   // fp32-staged kv, 64KB
  int tid = threadIdx.x;
  int bx = blockIdx.x; int chunk = bx & 15; int bh = bx >> 4;
  for(int idx = tid; idx < 16384; idx += 256) kv_l[idx] = kv[(size_t)bh*16384 + idx];
  __syncthreads();
  int wid = tid >> 6, lane = tid & 63;
  int b = bh >> 3, hh = bh & 7;
  float klsv = kls[bh];
  int t0 = chunk*256;
  for(int r = wid; r < 256; r += 4){
    int t = t0 + r;
    const float* qr = qp + ((size_t)bh*TT + t)*256;
    float q0 = qr[lane], q1 = qr[64 + lane], q2 = qr[128 + lane], q3 = qr[192 + lane];
    float qkv = 0.f;
    #pragma unroll 8
    for(int mm = 0; mm < 64; mm++){
      float c0 = __shfl(q0, mm, 64), c1 = __shfl(q1, mm, 64), c2 = __shfl(q2, mm, 64), c3 = __shfl(q3, mm, 64);
      qkv = fmaf(c0, kv_l[(      mm)*64 + lane], qkv);
      qkv = fmaf(c1, kv_l[( 64 + mm)*64 + lane], qkv);
      qkv = fmaf(c2, kv_l[(128 + mm)*64 + lane], qkv);
      qkv = fmaf(c3, kv_l[(192 + mm)*64 + lane], qkv);
    }
    float p1 = q0*ksum[bh*256 + lane] + q1*ksum[bh*256 + 64 + lane]
             + q2*ksum[bh*256 + 128 + lane] + q3*ksum[bh*256 + 192 + lane];
    #pragma unroll
    for(int o = 32; o > 0; o >>= 1) p1 += __shfl_xor(p1, o, 64);
    float l0 = lse_t[((size_t)0*TBH + bh)*TT + t], l1 = lse_t[((size_t)1*TBH + bh)*TT + t];
    float l2 = lse_t[((size_t)2*TBH + bh)*TT + t], l3 = lse_t[((size_t)3*TBH + bh)*TT + t];
    float M = fmaxf(fmaxf(l0, l1), fmaxf(l2, l3));
    float e0 = __expf(l0 - M), e1 = __expf(l1 - M), e2 = __expf(l2 - M), e3 = __expf(l3 - M);
    float rs = 1.f / (e0 + e1 + e2 + e3);
    float pr0 = e0*rs, pr1 = e1*rs, pr2 = e2*rs, pr3 = e3*rs;
    float psc = __expf(pls[bh*TT + t] + klsv - M)*rs;
    float outl = 0.f, nrm = 0.f;
    outl = fmaf(o_t[(((size_t)0*TBH + bh)*TT + t)*64 + lane], pr0, outl);
    outl = fmaf(o_t[(((size_t)1*TBH + bh)*TT + t)*64 + lane], pr1, outl);
    outl = fmaf(o_t[(((size_t)2*TBH + bh)*TT + t)*64 + lane], pr2, outl);
    outl = fmaf(o_t[(((size_t)3*TBH + bh)*TT + t)*64 + lane], pr3, outl);
    nrm  = fmaf(dsum_t[((size_t)0*TBH + bh)*TT + t], pr0, nrm);
    nrm  = fmaf(dsum_t[((size_t)1*TBH + bh)*TT + t], pr1, nrm);
    nrm  = fmaf(dsum_t[((size_t)2*TBH + bh)*TT + t], pr2, nrm);
    nrm  = fmaf(dsum_t[((size_t)3*TBH + bh)*TT + t], pr3, nrm);
    nrm  = fmaf(p1, psc, nrm);
    float res = (outl + qkv*psc) / fmaxf(nrm, 1e-6f);
    out[((size_t)(b*TT + t)*TH + hh)*64 + lane] = res;
  }
}

// sentinel: signals ws_size-too-small distinctly from a numeric bug
__global__ void k_sentinel(float* __restrict__ out, int n){
  int i = blockIdx.x*256 + threadIdx.x;
  if(i < n) out[i] = 12345.0f;
}

extern "C" void kernel_launch(void* const* d_in, const int* in_sizes, int n_in,
                              void* d_out, int out_size, void* d_ws, size_t ws_size,
                              hipStream_t stream){
  const float* q     = (const float*)d_in[0];
  const float* k     = (const float*)d_in[1];
  const float* v     = (const float*)d_in[2];
  const float* proj  = (const float*)d_in[3];
  const float* alpha = (const float*)d_in[4];
  const float* beta  = (const float*)d_in[5];
  float* out = (float*)d_out;
  char* ws = (char*)d_ws;

  if(ws_size < WS_NEED){
    k_sentinel<<<dim3((out_size + 255)/256), dim3(256), 0, stream>>>(out, out_size);
    return;
  }

  float*  qn2f  = (float*) (ws + OFF_QN2F);
  float*  kn2f  = (float*) (ws + OFF_KN2F);
  double* qn2d  = (double*)(ws + OFF_QN2D);
  double* kn2d  = (double*)(ws + OFF_KN2D);
  double* mqk2  = (double*)(ws + OFF_MQK2);
  double* qmaxp = (double*)(ws + OFF_QMAXP);
  double* kmaxp = (double*)(ws + OFF_KMAXP);
  double* qh    = (double*)(ws + OFF_QH);
  double* kh    = (double*)(ws + OFF_KH);
  int*   qpos   = (int*)  (ws + OFF_QPOS);
  int*   kpos   = (int*)  (ws + OFF_KPOS);
  int*   qrev   = (int*)  (ws + OFF_QREV);
  int*   krev   = (int*)  (ws + OFF_KREV);
  float* klsp   = (float*)(ws + OFF_KLSP);
  float* kls    = (float*)(ws + OFF_KLS);
  float* qp     = (float*)(ws + OFF_QP);
  float* kp     = (float*)(ws + OFF_KP);
  float* pls    = (float*)(ws + OFF_PLS);
  float* ksum   = (float*)(ws + OFF_KSUM);
  float* kvv    = (float*)(ws + OFF_KV);
  float* o_t    = (float*)(ws + OFF_OT);
  float* lse_t  = (float*)(ws + OFF_LSET);
  float* dsum_t = (float*)(ws + OFF_DSUM);

  k_norms2<<<dim3(256),  dim3(256), 0, stream>>>(q, k, qn2f, kn2f, qn2d, kn2d, qmaxp, kmaxp);
  k_mqk   <<<dim3(16),   dim3(64),  0, stream>>>(qmaxp, kmaxp, mqk2);
  k_hash  <<<dim3(512),  dim3(256), 0, stream>>>(q, k, alpha, beta, qn2d, kn2d, mqk2, qh, kh);
  k_sort  <<<dim3(128),  dim3(256), 0, stream>>>(qh, kh, qpos, kpos, qrev, krev);
  k_proj<1><<<dim3(2048), dim3(256), 0, stream>>>(k, proj, kn2f, nullptr, nullptr, klsp, nullptr);
  k_klsred<<<dim3(16),   dim3(128), 0, stream>>>(klsp, kls);
  k_proj<2><<<dim3(2048), dim3(256), 0, stream>>>(k, proj, kn2f, kls, kp, nullptr, nullptr);
  k_proj<0><<<dim3(2048), dim3(256), 0, stream>>>(q, proj, qn2f, nullptr, qp, nullptr, pls);
  k_kv    <<<dim3(256),  dim3(256), 0, stream>>>(kp, v, kvv, ksum);
  k_bucket<<<dim3(2048), dim3(256), 0, stream>>>(q, k, v, qp, kp, qpos, kpos, qrev, krev, pls, kls, o_t, lse_t, dsum_t);
  k_final <<<dim3(256),  dim3(256), 0, stream>>>(qp, kvv, ksum, o_t, lse_t, dsum_t, pls, kls, out);
}

// Round 4
// 1975.274 us; speedup vs baseline: 2.3446x; 2.0234x over previous
//
#include <hip/hip_runtime.h>
#include <stdint.h>
#include <math.h>

#define DEVI __device__ __forceinline__

// Problem constants (B,T,H,E fixed by the reference setup)
constexpr int TB  = 2;
constexpr int TT  = 4096;
constexpr int TH  = 8;
constexpr int TE  = 64;
constexpr int TBH = 16;   // B*H
constexpr int TM  = 256;  // performer features
constexpr int TNH = 4;    // hash rounds
constexpr float C_TEMP  = 0.125f;                 // 1/sqrt(E)
constexpr float C_DN    = 0.35355339059327373f;   // sqrt(temp)
constexpr float C_RATIO = 0.0625f;                // M^-0.5

// ---------------- workspace layout ----------------
constexpr size_t algn(size_t x){ return (x + 255) & ~(size_t)255; }
constexpr size_t OFF_QN2F = 0;
constexpr size_t OFF_KN2F = algn(OFF_QN2F + (size_t)TBH*TT*4);
constexpr size_t OFF_QN2D = algn(OFF_KN2F + (size_t)TBH*TT*4);
constexpr size_t OFF_KN2D = algn(OFF_QN2D + (size_t)TBH*TT*8);
constexpr size_t OFF_MQK2 = algn(OFF_KN2D + (size_t)TBH*TT*8);
constexpr size_t OFF_QMAXP= algn(OFF_MQK2 + (size_t)TBH*8);
constexpr size_t OFF_KMAXP= algn(OFF_QMAXP+ (size_t)TBH*16*8);
constexpr size_t OFF_QH   = algn(OFF_KMAXP+ (size_t)TBH*16*8);
constexpr size_t OFF_KH   = algn(OFF_QH   + (size_t)TNH*TBH*TT*8);
constexpr size_t OFF_QPOS = algn(OFF_KH   + (size_t)TNH*TBH*TT*8);
constexpr size_t OFF_KPOS = algn(OFF_QPOS + (size_t)TNH*TBH*TT*4);
constexpr size_t OFF_QREV = algn(OFF_KPOS + (size_t)TNH*TBH*TT*4);
constexpr size_t OFF_KREV = algn(OFF_QREV + (size_t)TNH*TBH*TT*4);
constexpr size_t OFF_KLSP = algn(OFF_KREV + (size_t)TNH*TBH*TT*4);
constexpr size_t OFF_KLS  = algn(OFF_KLSP + (size_t)TBH*128*4);
constexpr size_t OFF_QP   = algn(OFF_KLS  + (size_t)TBH*4);
constexpr size_t OFF_KP   = algn(OFF_QP   + (size_t)TBH*TT*TM*4);   // fp32, doubles as dashQ
constexpr size_t OFF_PLS  = algn(OFF_KP   + (size_t)TBH*TT*TM*4);   // kp doubles as dashK
constexpr size_t OFF_KSUM = algn(OFF_PLS  + (size_t)TBH*TT*4);
constexpr size_t OFF_KV   = algn(OFF_KSUM + (size_t)TBH*TM*4);
constexpr size_t OFF_OT   = algn(OFF_KV   + (size_t)TBH*TM*TE*4);
constexpr size_t OFF_LSET = algn(OFF_OT   + (size_t)TNH*TBH*TT*TE*4);
constexpr size_t OFF_DSUM = algn(OFF_LSET + (size_t)TNH*TBH*TT*4);
constexpr size_t WS_NEED  = algn(OFF_DSUM + (size_t)TNH*TBH*TT*4);  // ~203 MB

// ---------------- helpers ----------------
DEVI int dupc(uint32_t x){
  return (int)((x & 0xffu) == 0) + (int)(((x >> 8) & 0xffu) == 0)
       + (int)(((x >> 16) & 0xffu) == 0) + (int)((x >> 24) == 0);
}
DEVI float lndup(int d){
  return d == 1 ? 0.f : d == 2 ? 0.69314718f : d == 3 ? 1.09861229f : 1.38629436f;
}
DEVI float rcpdup(int d){
  return d == 1 ? 1.f : d == 2 ? 0.5f : d == 3 ? 0.333333343f : 0.25f;
}

DEVI float dot32f(const float* kr, const float4* q4){
  const float4* k4 = (const float4*)kr;
  float4 acc = make_float4(0.f,0.f,0.f,0.f);
  #pragma unroll
  for(int x = 0; x < 8; x++){
    float4 kv = k4[x], qv = q4[x];
    acc.x = fmaf(qv.x,kv.x,acc.x); acc.y = fmaf(qv.y,kv.y,acc.y);
    acc.z = fmaf(qv.z,kv.z,acc.z); acc.w = fmaf(qv.w,kv.w,acc.w);
  }
  return (acc.x + acc.y) + (acc.z + acc.w);
}

// ---------------- K1: row sumsq (f32+f64) + partial max (XBOX+ ext) ----------------
__global__ void k_norms2(const float* __restrict__ q, const float* __restrict__ kk,
                         float* __restrict__ qn2f, float* __restrict__ kn2f,
                         double* __restrict__ qn2d, double* __restrict__ kn2d,
                         double* __restrict__ qmaxp, double* __restrict__ kmaxp){
  __shared__ double red[256];
  int bx = blockIdx.x; int chunk = bx & 15, bh = bx >> 4;
  int tid = threadIdx.x;
  int b = bh >> 3, hh = bh & 7;
  int t = chunk*256 + tid;
  const float4* r1 = (const float4*)(q + (((size_t)(b*TT + t)*TH) + hh)*TE);
  double s = 0.0;
  #pragma unroll
  for(int x = 0; x < 16; x++){
    float4 vv = r1[x];
    s += (double)vv.x*vv.x + (double)vv.y*vv.y + (double)vv.z*vv.z + (double)vv.w*vv.w;
  }
  qn2d[bh*TT + t] = s; qn2f[bh*TT + t] = (float)s;
  const float4* r2 = (const float4*)(kk + (((size_t)(b*TT + t)*TH) + hh)*TE);
  double s2 = 0.0;
  #pragma unroll
  for(int x = 0; x < 16; x++){
    float4 vv = r2[x];
    s2 += (double)vv.x*vv.x + (double)vv.y*vv.y + (double)vv.z*vv.z + (double)vv.w*vv.w;
  }
  kn2d[bh*TT + t] = s2; kn2f[bh*TT + t] = (float)s2;
  red[tid] = s; __syncthreads();
  for(int o = 128; o > 0; o >>= 1){ if(tid < o) red[tid] = fmax(red[tid], red[tid+o]); __syncthreads(); }
  if(tid == 0) qmaxp[bh*16 + chunk] = red[0];
  __syncthreads();
  red[tid] = s2; __syncthreads();
  for(int o = 128; o > 0; o >>= 1){ if(tid < o) red[tid] = fmax(red[tid], red[tid+o]); __syncthreads(); }
  if(tid == 0) kmaxp[bh*16 + chunk] = red[0];
}

__global__ void k_mqk(const double* __restrict__ qmaxp, const double* __restrict__ kmaxp,
                      double* __restrict__ mqk2){
  int bh = blockIdx.x;
  if(threadIdx.x == 0){
    double mq = -1e300, mk = -1e300;
    for(int i = 0; i < 16; i++){ mq = fmax(mq, qmaxp[bh*16 + i]); mk = fmax(mk, kmaxp[bh*16 + i]); }
    mqk2[bh] = mq + mk;
  }
}

// ---------------- K2: E2LSH hashes (float64) ----------------
__global__ void k_hash(const float* __restrict__ q, const float* __restrict__ kk,
                       const float* __restrict__ alpha, const float* __restrict__ beta,
                       const double* __restrict__ qn2d, const double* __restrict__ kn2d,
                       const double* __restrict__ mqk2,
                       double* __restrict__ qh, double* __restrict__ kh){
  __shared__ double al[264];
  __shared__ double be[4];
  int tid = threadIdx.x;
  for(int i = tid; i < 264; i += 256) al[i] = (double)alpha[i];
  if(tid < 4) be[tid] = (double)beta[tid];
  __syncthreads();
  int gid = blockIdx.x*256 + tid;
  int side = gid >> 16; int r = gid & 65535;
  int bh = r >> 12, t = r & 4095;
  int b = bh >> 3, hh = bh & 7;
  const float* x = (side ? kk : q) + (((size_t)(b*TT + t)*TH) + hh)*TE;
  const float4* xr = (const float4*)x;
  double a0 = 0.0, a1 = 0.0, a2 = 0.0, a3 = 0.0;
  #pragma unroll
  for(int c = 0; c < 16; c++){
    float4 vv = xr[c];
    const double* a = al + c*16;
    a0 += (double)vv.x*a[0]  + (double)vv.y*a[4]  + (double)vv.z*a[8]  + (double)vv.w*a[12];
    a1 += (double)vv.x*a[1]  + (double)vv.y*a[5]  + (double)vv.z*a[9]  + (double)vv.w*a[13];
    a2 += (double)vv.x*a[2]  + (double)vv.y*a[6]  + (double)vv.z*a[10] + (double)vv.w*a[14];
    a3 += (double)vv.x*a[3]  + (double)vv.y*a[7]  + (double)vv.z*a[11] + (double)vv.w*a[15];
  }
  double n2  = (side ? kn2d : qn2d)[bh*TT + t];
  double ext = sqrt(fmax(mqk2[bh] - n2, 0.0));
  int ec = side ? 65 : 64;
  double* dst = side ? kh : qh;
  dst[((size_t)0*TBH + bh)*TT + t] = a0 + ext*al[ec*4 + 0] + be[0];
  dst[((size_t)1*TBH + bh)*TT + t] = a1 + ext*al[ec*4 + 1] + be[1];
  dst[((size_t)2*TBH + bh)*TT + t] = a2 + ext*al[ec*4 + 2] + be[2];
  dst[((size_t)3*TBH + bh)*TT + t] = a3 + ext*al[ec*4 + 3] + be[3];
}

// ---------------- K3: stable argsort via bitonic on doubles ----------------
__global__ void k_sort(const double* __restrict__ qh, const double* __restrict__ kh,
                       int* __restrict__ qpos, int* __restrict__ kpos,
                       int* __restrict__ qrev, int* __restrict__ krev){
  __shared__ double v[4096];
  __shared__ int    ix[4096];
  int blk = blockIdx.x; int side = blk >> 6; int hb = blk & 63;
  const double* src = (side ? kh : qh) + (size_t)hb*TT;
  int tid = threadIdx.x;
  for(int i = tid; i < 4096; i += 256){ v[i] = src[i]; ix[i] = i; }
  __syncthreads();
  for(int k = 2; k <= 4096; k <<= 1){
    for(int j = k >> 1; j > 0; j >>= 1){
      for(int i = tid; i < 4096; i += 256){
        int l = i ^ j;
        if(l > i){
          double va = v[i], vb = v[l]; int ia = ix[i], ib = ix[l];
          bool gt  = (va > vb) || (va == vb && ia > ib);
          bool asc = ((i & k) == 0);
          if(gt == asc){ v[i] = vb; v[l] = va; ix[i] = ib; ix[l] = ia; }
        }
      }
      __syncthreads();
    }
  }
  int* pos = (side ? kpos : qpos) + (size_t)hb*TT;
  int* rev = (side ? krev : qrev) + (size_t)hb*TT;
  for(int i = tid; i < 4096; i += 256){ int id = ix[i]; pos[i] = id; rev[id] = i; }
}

// ---------------- K4: dash GEMM (both sides) -> dash[bh][t][m] ----------------
// 64t x 256m tile, K=64. proj transposed into LDS once; per-thread 4x4 float4
// accumulator. fmaf chain is e-ascending per output (bit-identical to the
// previous passing version's chain). dash written in place into qp/kp buffers.
__launch_bounds__(256, 2)
__global__ void k_dash(const float* __restrict__ q, const float* __restrict__ kk,
                       const float* __restrict__ proj,
                       const float* __restrict__ qn2f, const float* __restrict__ kn2f,
                       float* __restrict__ qdash, float* __restrict__ kdash){
  __shared__ __align__(16) float pjL[64*260];   // pjL[e][m], pad 4 -> 66.6 KB
  __shared__ __align__(16) float x_l[64*68];    // x rows, pad 4 -> 17.4 KB
  __shared__ float x_n[64];
  int tid = threadIdx.x;
  int bx = blockIdx.x;
  int side = bx >> 10; int r = bx & 1023; int bh = r >> 6; int ch = r & 63;
  int b = bh >> 3, hh = bh & 7, t0 = ch*64;
  const float* x  = side ? kk   : q;
  const float* n2 = side ? kn2f : qn2f;
  float* outp     = side ? kdash : qdash;

  #pragma unroll 8
  for(int it = 0; it < 64; it++){
    int idx = it*256 + tid;
    pjL[(idx & 63)*260 + (idx >> 6)] = proj[idx];
  }
  {
    int rr = tid >> 2, c = tid & 3;
    const float4* src = (const float4*)(x + (((size_t)(b*TT + t0 + rr)*TH) + hh)*TE);
    float4* dst = (float4*)(x_l + rr*68);
    #pragma unroll
    for(int i = 0; i < 4; i++) dst[c*4 + i] = src[c*4 + i];
  }
  if(tid < 64) x_n[tid] = n2[bh*TT + t0 + tid];
  __syncthreads();

  int ml = (tid & 15)*4;   // m base (within 64-col group)
  int tb = tid >> 4;       // 0..15 t-base
  float4 acc[4][4];
  #pragma unroll
  for(int tt = 0; tt < 4; tt++)
    #pragma unroll
    for(int g = 0; g < 4; g++) acc[tt][g] = make_float4(0.f,0.f,0.f,0.f);

  #pragma unroll 4
  for(int k4 = 0; k4 < 16; k4++){
    float4 xv[4];
    #pragma unroll
    for(int tt = 0; tt < 4; tt++)
      xv[tt] = *((const float4*)(x_l + (tb + 16*tt)*68 + k4*4));
    #pragma unroll
    for(int kk4 = 0; kk4 < 4; kk4++){
      int krow = k4*4 + kk4;
      #pragma unroll
      for(int g = 0; g < 4; g++){
        float4 pv = *((const float4*)(pjL + krow*260 + ml + 64*g));
        #pragma unroll
        for(int tt = 0; tt < 4; tt++){
          float xs = (kk4 == 0) ? xv[tt].x : (kk4 == 1) ? xv[tt].y : (kk4 == 2) ? xv[tt].z : xv[tt].w;
          acc[tt][g].x = fmaf(xs, pv.x, acc[tt][g].x);
          acc[tt][g].y = fmaf(xs, pv.y, acc[tt][g].y);
          acc[tt][g].z = fmaf(xs, pv.z, acc[tt][g].z);
          acc[tt][g].w = fmaf(xs, pv.w, acc[tt][g].w);
        }
      }
    }
  }
  #pragma unroll
  for(int tt = 0; tt < 4; tt++){
    int t_r = tb + 16*tt;
    float diag = 0.5f*C_TEMP*x_n[t_r];
    size_t rowbase = ((size_t)bh*TT + t0 + t_r)*256;
    #pragma unroll
    for(int g = 0; g < 4; g++){
      float4 a = acc[tt][g];
      float4 dd;
      dd.x = fmaf(C_DN, a.x, -diag); dd.y = fmaf(C_DN, a.y, -diag);
      dd.z = fmaf(C_DN, a.z, -diag); dd.w = fmaf(C_DN, a.w, -diag);
      *((float4*)(outp + rowbase + ml + 64*g)) = dd;
    }
  }
}

// ---------------- K4b: max over dashK chunks -> klsp ----------------
__global__ void k_klsmax(const float* __restrict__ kdash, float* __restrict__ klsp){
  __shared__ float wr[4];
  int tid = threadIdx.x;
  int bx = blockIdx.x; int bh = bx >> 7, ch = bx & 127;
  const float4* src = (const float4*)(kdash + ((size_t)bh << 20)) + ch*2048;
  float mx = -1e30f;
  #pragma unroll
  for(int i = 0; i < 8; i++){
    float4 vv = src[i*256 + tid];
    mx = fmaxf(mx, fmaxf(fmaxf(vv.x, vv.y), fmaxf(vv.z, vv.w)));
  }
  #pragma unroll
  for(int o = 32; o > 0; o >>= 1) mx = fmaxf(mx, __shfl_xor(mx, o, 64));
  if((tid & 63) == 0) wr[tid >> 6] = mx;
  __syncthreads();
  if(tid == 0) klsp[bh*128 + ch] = fmaxf(fmaxf(wr[0], wr[1]), fmaxf(wr[2], wr[3]));
}

__global__ void k_klsred(const float* __restrict__ klsp, float* __restrict__ kls){
  __shared__ float red[2];
  int bh = blockIdx.x, tid = threadIdx.x;
  float v = klsp[bh*128 + tid];
  #pragma unroll
  for(int o = 32; o > 0; o >>= 1) v = fmaxf(v, __shfl_xor(v, o, 64));
  if((tid & 63) == 0) red[tid >> 6] = v;
  __syncthreads();
  if(tid == 0) kls[bh] = fmaxf(red[0], red[1]);
}

// ---------------- K4c: kp = exp(dashK - kls)*ratio, in place ----------------
__global__ void k_expk(float* __restrict__ kp, const float* __restrict__ kls){
  int tid = threadIdx.x; int blk = blockIdx.x;
  float4* p = (float4*)kp;
  size_t base = (size_t)blk*2048;
  float stab = kls[blk >> 7];
  #pragma unroll
  for(int i = 0; i < 8; i++){
    size_t ix = base + i*256 + tid;
    float4 vv = p[ix];
    vv.x = __expf(vv.x - stab)*C_RATIO; vv.y = __expf(vv.y - stab)*C_RATIO;
    vv.z = __expf(vv.z - stab)*C_RATIO; vv.w = __expf(vv.w - stab)*C_RATIO;
    p[ix] = vv;
  }
}

// ---------------- K4d: qp = exp(dashQ - rowmax)*ratio in place, pls = rowmax ----------------
__global__ void k_expq(float* __restrict__ qp, float* __restrict__ pls){
  int tid = threadIdx.x, wid = tid >> 6, lane = tid & 63;
  int row = blockIdx.x*4 + wid;
  float4* p = (float4*)(qp + (size_t)row*256);
  float4 vv = p[lane];
  float mr = fmaxf(fmaxf(vv.x, vv.y), fmaxf(vv.z, vv.w));
  #pragma unroll
  for(int o = 32; o > 0; o >>= 1) mr = fmaxf(mr, __shfl_xor(mr, o, 64));
  float4 rr;
  rr.x = __expf(vv.x - mr)*C_RATIO; rr.y = __expf(vv.y - mr)*C_RATIO;
  rr.z = __expf(vv.z - mr)*C_RATIO; rr.w = __expf(vv.w - mr)*C_RATIO;
  p[lane] = rr;
  if(lane == 0) pls[row] = mr;
}

// ---------------- K5: kv = k'^T v, ksum = sum_s k' ----------------
__global__ void k_kv(const float* __restrict__ kp, const float* __restrict__ v,
                     float* __restrict__ kv, float* __restrict__ ksum){
  int bx = blockIdx.x; int mt = bx & 7; int bh = bx >> 3;
  int tid = threadIdx.x; int g = tid >> 6, d = tid & 63;
  int b = bh >> 3, hh = bh & 7; int m0 = mt*32;
  float a[8], sa[8];
  #pragma unroll
  for(int j = 0; j < 8; j++){ a[j] = 0.f; sa[j] = 0.f; }
  const float* kpb = kp + (size_t)bh*TT*256 + m0 + g;
  const float* vb  = v + (size_t)b*TT*TH*TE + hh*TE + d;
  #pragma unroll 4
  for(int s = 0; s < TT; s++){
    float vv = vb[(size_t)s*512];
    const float* kr = kpb + (size_t)s*256;
    #pragma unroll
    for(int j = 0; j < 8; j++){
      float kj = kr[4*j];
      a[j] = fmaf(kj, vv, a[j]); sa[j] += kj;
    }
  }
  #pragma unroll
  for(int j = 0; j < 8; j++){
    int m = m0 + g + 4*j;
    kv[((size_t)bh*256 + m)*64 + d] = a[j];
    if(d == 0) ksum[bh*256 + m] = sa[j];
  }
}

// ---------------- K6: per-bucket attention (all fp32, UB stabilizer) ----------------
__launch_bounds__(256, 2)
__global__ void k_bucket(const float* __restrict__ q, const float* __restrict__ kk, const float* __restrict__ v,
                         const float* __restrict__ qp, const float* __restrict__ kp,
                         const int* __restrict__ qpos, const int* __restrict__ kpos,
                         const int* __restrict__ qrev, const int* __restrict__ krev,
                         const float* __restrict__ pls, const float* __restrict__ kls,
                         const float* __restrict__ qn2f, const float* __restrict__ kn2f,
                         float* __restrict__ o_t, float* __restrict__ lse_t, float* __restrict__ dsum_t){
  __shared__ float k_l[128*64];
  __shared__ float v_l[128*64];
  __shared__ float kp_l[8*256];
  __shared__ int   kidx[128];
  __shared__ int   kbp[128];
  __shared__ float kn2v[128];
  __shared__ float kmaxS;
  int tid = threadIdx.x;
  int bx = blockIdx.x; int n = bx & 31, bh = (bx >> 5) & 15, h = bx >> 9;
  int b = bh >> 3, hh = bh & 7;

  if(tid < 128){
    int tk = kpos[((size_t)h*TBH + bh)*TT + n*128 + tid];
    kidx[tid] = tk;
    int pk = 0;
    #pragma unroll
    for(int h3 = 0; h3 < 4; h3++){ int rv = krev[((size_t)h3*TBH + bh)*TT + tk]; pk |= (rv >> 7) << (8*h3); }
    kbp[tid] = pk;
    kn2v[tid] = kn2f[(size_t)bh*TT + tk];
  }
  __syncthreads();
  if(tid < 64){
    float m = fmaxf(kn2v[tid], kn2v[tid + 64]);
    #pragma unroll
    for(int o = 32; o > 0; o >>= 1) m = fmaxf(m, __shfl_xor(m, o, 64));
    if(tid == 0) kmaxS = m;
  }
  {
    int c = tid & 15, r0 = tid >> 4;
    for(int r = r0; r < 128; r += 16){
      int tk = kidx[r];
      const float4* sk = (const float4*)(kk + (((size_t)(b*TT + tk)*TH) + hh)*TE);
      const float4* sv = (const float4*)(v  + (((size_t)(b*TT + tk)*TH) + hh)*TE);
      *((float4*)(k_l + r*64 + c*4)) = sk[c];
      *((float4*)(v_l + r*64 + c*4)) = sv[c];
    }
  }

  int i  = tid >> 1, h2 = tid & 1;
  int slot = n*128 + i;
  int tq = qpos[((size_t)h*TBH + bh)*TT + slot];
  float4 q4[8];
  { const float4* qs = (const float4*)(q + (((size_t)(b*TT + tq)*TH) + hh)*TE + h2*32);
    #pragma unroll
    for(int x = 0; x < 8; x++) q4[x] = qs[x]; }
  float4 qp4[32];
  { const float4* ps = (const float4*)(qp + ((size_t)bh*TT + tq)*256 + h2*128);
    #pragma unroll
    for(int x = 0; x < 32; x++) qp4[x] = ps[x]; }
  float plsv = pls[(size_t)bh*TT + tq] + kls[bh];
  float qn2row = qn2f[(size_t)bh*TT + tq];
  int qbp = 0;
  #pragma unroll
  for(int h3 = 0; h3 < 4; h3++){ int rv = qrev[((size_t)h3*TBH + bh)*TT + tq]; qbp |= (rv >> 7) << (8*h3); }
  __syncthreads();

  // Stabilizer: Cauchy-Schwarz upper bound of inner (result is algebraically
  // invariant to lse; bound >= inner guarantees exp args <= ~0, no overflow).
  float lse = fmaxf(plsv, C_TEMP * sqrtf(qn2row * kmaxS));

  float pfac = __expf(plsv - lse);
  float dsum = 0.f;
  float4 so[8];
  #pragma unroll
  for(int x = 0; x < 8; x++) so[x] = make_float4(0.f,0.f,0.f,0.f);
  for(int jt = 0; jt < 16; jt++){
    __syncthreads();
    { int jj = tid >> 5, c = tid & 31;
      int tk = kidx[jt*8 + jj];
      const float4* src = (const float4*)(kp + ((size_t)bh*TT + tk)*256);
      float4 u0 = src[c*2], u1 = src[c*2 + 1];
      float4* dst = (float4*)(kp_l + jj*256 + c*8);
      dst[0] = u0; dst[1] = u1;
    }
    __syncthreads();
    #pragma unroll 2
    for(int jj = 0; jj < 8; jj++){
      int j = jt*8 + jj;
      float s = dot32f(k_l + j*64 + h2*32, q4);
      s += __shfl_xor(s, 1, 64);
      float4 pa = make_float4(0.f,0.f,0.f,0.f);
      const float4* prr = (const float4*)(kp_l + jj*256 + h2*128);
      #pragma unroll
      for(int x = 0; x < 32; x++){
        float4 pv = prr[x];
        pa.x = fmaf(qp4[x].x, pv.x, pa.x); pa.y = fmaf(qp4[x].y, pv.y, pa.y);
        pa.z = fmaf(qp4[x].z, pv.z, pa.z); pa.w = fmaf(qp4[x].w, pv.w, pa.w);
      }
      float dp = (pa.x + pa.y) + (pa.z + pa.w);
      dp += __shfl_xor(dp, 1, 64);
      int du = dupc((uint32_t)(qbp ^ kbp[j]));
      float ein  = __expf(fmaf(C_TEMP, s, -lndup(du)) - lse);
      float dots = fmaf(-dp*rcpdup(du), pfac, ein);
      dsum += dots;
      const float4* vr = (const float4*)(v_l + j*64 + h2*32);
      #pragma unroll
      for(int x = 0; x < 8; x++){
        float4 vA = vr[x];
        so[x].x = fmaf(dots, vA.x, so[x].x); so[x].y = fmaf(dots, vA.y, so[x].y);
        so[x].z = fmaf(dots, vA.z, so[x].z); so[x].w = fmaf(dots, vA.w, so[x].w);
      }
    }
  }
  size_t ob = ((((size_t)h*TBH + bh)*TT) + tq)*64 + h2*32;
  float4* od = (float4*)(o_t + ob);
  #pragma unroll
  for(int x = 0; x < 8; x++) od[x] = so[x];
  if(h2 == 0){
    lse_t [((size_t)h*TBH + bh)*TT + tq] = lse;
    dsum_t[((size_t)h*TBH + bh)*TT + tq] = dsum;
  }
}

// ---------------- K7: combine hash rounds + performer term ----------------
__global__ void k_final(const float* __restrict__ qp, const float* __restrict__ kv,
                        const float* __restrict__ ksum, const float* __restrict__ o_t,
                        const float* __restrict__ lse_t, const float* __restrict__ dsum_t,
                        const float* __restrict__ pls, const float* __restrict__ kls,
                        float* __restrict__ out){
  __shared__ float kv_l[256*64];
  int tid = threadIdx.x;
  int bx = blockIdx.x; int chunk = bx & 15; int bh = bx >> 4;
  for(int idx = tid; idx < 16384; idx += 256) kv_l[idx] = kv[(size_t)bh*16384 + idx];
  __syncthreads();
  int wid = tid >> 6, lane = tid & 63;
  int b = bh >> 3, hh = bh & 7;
  float klsv = kls[bh];
  int t0 = chunk*256;
  for(int r = wid; r < 256; r += 4){
    int t = t0 + r;
    const float* qr = qp + ((size_t)bh*TT + t)*256;
    float q0 = qr[lane], q1 = qr[64 + lane], q2 = qr[128 + lane], q3 = qr[192 + lane];
    float qkv = 0.f;
    #pragma unroll 8
    for(int mm = 0; mm < 64; mm++){
      float c0 = __shfl(q0, mm, 64), c1 = __shfl(q1, mm, 64), c2 = __shfl(q2, mm, 64), c3 = __shfl(q3, mm, 64);
      qkv = fmaf(c0, kv_l[(      mm)*64 + lane], qkv);
      qkv = fmaf(c1, kv_l[( 64 + mm)*64 + lane], qkv);
      qkv = fmaf(c2, kv_l[(128 + mm)*64 + lane], qkv);
      qkv = fmaf(c3, kv_l[(192 + mm)*64 + lane], qkv);
    }
    float p1 = q0*ksum[bh*256 + lane] + q1*ksum[bh*256 + 64 + lane]
             + q2*ksum[bh*256 + 128 + lane] + q3*ksum[bh*256 + 192 + lane];
    #pragma unroll
    for(int o = 32; o > 0; o >>= 1) p1 += __shfl_xor(p1, o, 64);
    float l0 = lse_t[((size_t)0*TBH + bh)*TT + t], l1 = lse_t[((size_t)1*TBH + bh)*TT + t];
    float l2 = lse_t[((size_t)2*TBH + bh)*TT + t], l3 = lse_t[((size_t)3*TBH + bh)*TT + t];
    float M = fmaxf(fmaxf(l0, l1), fmaxf(l2, l3));
    float e0 = __expf(l0 - M), e1 = __expf(l1 - M), e2 = __expf(l2 - M), e3 = __expf(l3 - M);
    float rs = 1.f / (e0 + e1 + e2 + e3);
    float pr0 = e0*rs, pr1 = e1*rs, pr2 = e2*rs, pr3 = e3*rs;
    float psc = __expf(pls[bh*TT + t] + klsv - M)*rs;
    float outl = 0.f, nrm = 0.f;
    outl = fmaf(o_t[(((size_t)0*TBH + bh)*TT + t)*64 + lane], pr0, outl);
    outl = fmaf(o_t[(((size_t)1*TBH + bh)*TT + t)*64 + lane], pr1, outl);
    outl = fmaf(o_t[(((size_t)2*TBH + bh)*TT + t)*64 + lane], pr2, outl);
    outl = fmaf(o_t[(((size_t)3*TBH + bh)*TT + t)*64 + lane], pr3, outl);
    nrm  = fmaf(dsum_t[((size_t)0*TBH + bh)*TT + t], pr0, nrm);
    nrm  = fmaf(dsum_t[((size_t)1*TBH + bh)*TT + t], pr1, nrm);
    nrm  = fmaf(dsum_t[((size_t)2*TBH + bh)*TT + t], pr2, nrm);
    nrm  = fmaf(dsum_t[((size_t)3*TBH + bh)*TT + t], pr3, nrm);
    nrm  = fmaf(p1, psc, nrm);
    float res = (outl + qkv*psc) / fmaxf(nrm, 1e-6f);
    out[((size_t)(b*TT + t)*TH + hh)*64 + lane] = res;
  }
}

// sentinel: signals ws_size-too-small distinctly from a numeric bug
__global__ void k_sentinel(float* __restrict__ out, int n){
  int i = blockIdx.x*256 + threadIdx.x;
  if(i < n) out[i] = 12345.0f;
}

extern "C" void kernel_launch(void* const* d_in, const int* in_sizes, int n_in,
                              void* d_out, int out_size, void* d_ws, size_t ws_size,
                              hipStream_t stream){
  const float* q     = (const float*)d_in[0];
  const float* k     = (const float*)d_in[1];
  const float* v     = (const float*)d_in[2];
  const float* proj  = (const float*)d_in[3];
  const float* alpha = (const float*)d_in[4];
  const float* beta  = (const float*)d_in[5];
  float* out = (float*)d_out;
  char* ws = (char*)d_ws;

  if(ws_size < WS_NEED){
    k_sentinel<<<dim3((out_size + 255)/256), dim3(256), 0, stream>>>(out, out_size);
    return;
  }

  float*  qn2f  = (float*) (ws + OFF_QN2F);
  float*  kn2f  = (float*) (ws + OFF_KN2F);
  double* qn2d  = (double*)(ws + OFF_QN2D);
  double* kn2d  = (double*)(ws + OFF_KN2D);
  double* mqk2  = (double*)(ws + OFF_MQK2);
  double* qmaxp = (double*)(ws + OFF_QMAXP);
  double* kmaxp = (double*)(ws + OFF_KMAXP);
  double* qh    = (double*)(ws + OFF_QH);
  double* kh    = (double*)(ws + OFF_KH);
  int*   qpos   = (int*)  (ws + OFF_QPOS);
  int*   kpos   = (int*)  (ws + OFF_KPOS);
  int*   qrev   = (int*)  (ws + OFF_QREV);
  int*   krev   = (int*)  (ws + OFF_KREV);
  float* klsp   = (float*)(ws + OFF_KLSP);
  float* kls    = (float*)(ws + OFF_KLS);
  float* qp     = (float*)(ws + OFF_QP);   // doubles as dashQ
  float* kp     = (float*)(ws + OFF_KP);   // doubles as dashK
  float* pls    = (float*)(ws + OFF_PLS);
  float* ksum   = (float*)(ws + OFF_KSUM);
  float* kvv    = (float*)(ws + OFF_KV);
  float* o_t    = (float*)(ws + OFF_OT);
  float* lse_t  = (float*)(ws + OFF_LSET);
  float* dsum_t = (float*)(ws + OFF_DSUM);

  k_norms2<<<dim3(256),   dim3(256), 0, stream>>>(q, k, qn2f, kn2f, qn2d, kn2d, qmaxp, kmaxp);
  k_mqk   <<<dim3(16),    dim3(64),  0, stream>>>(qmaxp, kmaxp, mqk2);
  k_hash  <<<dim3(512),   dim3(256), 0, stream>>>(q, k, alpha, beta, qn2d, kn2d, mqk2, qh, kh);
  k_sort  <<<dim3(128),   dim3(256), 0, stream>>>(qh, kh, qpos, kpos, qrev, krev);
  k_dash  <<<dim3(2048),  dim3(256), 0, stream>>>(q, k, proj, qn2f, kn2f, qp, kp);
  k_klsmax<<<dim3(2048),  dim3(256), 0, stream>>>(kp, klsp);
  k_klsred<<<dim3(16),    dim3(128), 0, stream>>>(klsp, kls);
  k_expk  <<<dim3(2048),  dim3(256), 0, stream>>>(kp, kls);
  k_expq  <<<dim3(16384), dim3(256), 0, stream>>>(qp, pls);
  k_kv    <<<dim3(128),   dim3(256), 0, stream>>>(kp, v, kvv, ksum);
  k_bucket<<<dim3(2048),  dim3(256), 0, stream>>>(q, k, v, qp, kp, qpos, kpos, qrev, krev, pls, kls, qn2f, kn2f, o_t, lse_t, dsum_t);
  k_final <<<dim3(256),   dim3(256), 0, stream>>>(qp, kvv, ksum, o_t, lse_t, dsum_t, pls, kls, out);
}

// Round 5
// 999.705 us; speedup vs baseline: 4.6327x; 1.9759x over previous
//
#include <hip/hip_runtime.h>
#include <stdint.h>
#include <math.h>

#define DEVI __device__ __forceinline__

// Problem constants (B,T,H,E fixed by the reference setup)
constexpr int TB  = 2;
constexpr int TT  = 4096;
constexpr int TH  = 8;
constexpr int TE  = 64;
constexpr int TBH = 16;   // B*H
constexpr int TM  = 256;  // performer features
constexpr int TNH = 4;    // hash rounds
constexpr float C_TEMP  = 0.125f;                 // 1/sqrt(E)
constexpr float C_DN    = 0.35355339059327373f;   // sqrt(temp)
constexpr float C_RATIO = 0.0625f;                // M^-0.5

typedef __attribute__((ext_vector_type(8))) short bf16x8;
typedef __attribute__((ext_vector_type(4))) float f32x4;

// ---------------- workspace layout ----------------
constexpr size_t algn(size_t x){ return (x + 255) & ~(size_t)255; }
constexpr size_t OFF_QN2F = 0;
constexpr size_t OFF_KN2F = algn(OFF_QN2F + (size_t)TBH*TT*4);
constexpr size_t OFF_QN2D = algn(OFF_KN2F + (size_t)TBH*TT*4);
constexpr size_t OFF_KN2D = algn(OFF_QN2D + (size_t)TBH*TT*8);
constexpr size_t OFF_MQK2 = algn(OFF_KN2D + (size_t)TBH*TT*8);
constexpr size_t OFF_QMAXP= algn(OFF_MQK2 + (size_t)TBH*8);
constexpr size_t OFF_KMAXP= algn(OFF_QMAXP+ (size_t)TBH*16*8);
constexpr size_t OFF_QH   = algn(OFF_KMAXP+ (size_t)TBH*16*8);
constexpr size_t OFF_KH   = algn(OFF_QH   + (size_t)TNH*TBH*TT*8);
constexpr size_t OFF_QPOS = algn(OFF_KH   + (size_t)TNH*TBH*TT*8);
constexpr size_t OFF_KPOS = algn(OFF_QPOS + (size_t)TNH*TBH*TT*4);
constexpr size_t OFF_QREV = algn(OFF_KPOS + (size_t)TNH*TBH*TT*4);
constexpr size_t OFF_KREV = algn(OFF_QREV + (size_t)TNH*TBH*TT*4);
constexpr size_t OFF_KLSP = algn(OFF_KREV + (size_t)TNH*TBH*TT*4);
constexpr size_t OFF_KLS  = algn(OFF_KLSP + (size_t)TBH*128*4);
constexpr size_t OFF_QP   = algn(OFF_KLS  + (size_t)TBH*4);
constexpr size_t OFF_KP   = algn(OFF_QP   + (size_t)TBH*TT*TM*4);   // fp32, doubles as dashQ
constexpr size_t OFF_PLS  = algn(OFF_KP   + (size_t)TBH*TT*TM*4);   // kp doubles as dashK
constexpr size_t OFF_KSUM = algn(OFF_PLS  + (size_t)TBH*TT*4);
constexpr size_t OFF_KV   = algn(OFF_KSUM + (size_t)TBH*TM*4);
constexpr size_t OFF_OT   = algn(OFF_KV   + (size_t)TBH*TM*TE*4);
constexpr size_t OFF_LSET = algn(OFF_OT   + (size_t)TNH*TBH*TT*TE*4);
constexpr size_t OFF_DSUM = algn(OFF_LSET + (size_t)TNH*TBH*TT*4);
constexpr size_t WS_NEED  = algn(OFF_DSUM + (size_t)TNH*TBH*TT*4);  // ~203 MB
// overlays (dead after k_sort/k_hash): kv partials in qn2d..kh window
constexpr size_t OFF_KVP  = OFF_QN2D;                  // 4 MB (4 x 16 x 256 x 64 f32)
constexpr size_t OFF_KSP  = OFF_KVP + (size_t)4*16*256*64*4;  // 64 KB

// ---------------- helpers ----------------
DEVI float bf2f(uint32_t u16){ uint32_t x = u16 << 16; return __builtin_bit_cast(float, x); }
DEVI uint16_t f2bf(float f){
  uint32_t x = __builtin_bit_cast(uint32_t, f);
  uint32_t r = x + 0x7fffu + ((x >> 16) & 1u);   // RNE
  return (uint16_t)(r >> 16);
}
DEVI int dupc(uint32_t x){
  return (int)((x & 0xffu) == 0) + (int)(((x >> 8) & 0xffu) == 0)
       + (int)(((x >> 16) & 0xffu) == 0) + (int)((x >> 24) == 0);
}
DEVI float lndup(int d){
  return d == 1 ? 0.f : d == 2 ? 0.69314718f : d == 3 ? 1.09861229f : 1.38629436f;
}
DEVI float rcpdup(int d){
  return d == 1 ? 1.f : d == 2 ? 0.5f : d == 3 ? 0.333333343f : 0.25f;
}

// stage 32 floats (half of a 64-wide row) as bf16 hi|lo into a 272B LDS row:
// layout per row: 64 hi shorts | 64 lo shorts | 8 pad shorts
DEVI void stage64(char* rowp, const float4* src8, int hf){
  #pragma unroll
  for(int x = 0; x < 8; x++){
    float4 vv = src8[x];
    uint16_t hx = f2bf(vv.x), hy = f2bf(vv.y), hz = f2bf(vv.z), hw = f2bf(vv.w);
    float lx = vv.x - bf2f(hx), ly = vv.y - bf2f(hy), lz = vv.z - bf2f(hz), lw = vv.w - bf2f(hw);
    uint2 hp = make_uint2((uint32_t)hx | ((uint32_t)hy << 16), (uint32_t)hz | ((uint32_t)hw << 16));
    uint2 lp = make_uint2((uint32_t)f2bf(lx) | ((uint32_t)f2bf(ly) << 16),
                          (uint32_t)f2bf(lz) | ((uint32_t)f2bf(lw) << 16));
    *((uint2*)(rowp + 64*hf + 8*x)) = hp;
    *((uint2*)(rowp + 128 + 64*hf + 8*x)) = lp;
  }
}

// ---------------- K1: row sumsq (f32+f64) + partial max (XBOX+ ext) ----------------
__global__ void k_norms2(const float* __restrict__ q, const float* __restrict__ kk,
                         float* __restrict__ qn2f, float* __restrict__ kn2f,
                         double* __restrict__ qn2d, double* __restrict__ kn2d,
                         double* __restrict__ qmaxp, double* __restrict__ kmaxp){
  __shared__ double red[256];
  int bx = blockIdx.x; int chunk = bx & 15, bh = bx >> 4;
  int tid = threadIdx.x;
  int b = bh >> 3, hh = bh & 7;
  int t = chunk*256 + tid;
  const float4* r1 = (const float4*)(q + (((size_t)(b*TT + t)*TH) + hh)*TE);
  double s = 0.0;
  #pragma unroll
  for(int x = 0; x < 16; x++){
    float4 vv = r1[x];
    s += (double)vv.x*vv.x + (double)vv.y*vv.y + (double)vv.z*vv.z + (double)vv.w*vv.w;
  }
  qn2d[bh*TT + t] = s; qn2f[bh*TT + t] = (float)s;
  const float4* r2 = (const float4*)(kk + (((size_t)(b*TT + t)*TH) + hh)*TE);
  double s2 = 0.0;
  #pragma unroll
  for(int x = 0; x < 16; x++){
    float4 vv = r2[x];
    s2 += (double)vv.x*vv.x + (double)vv.y*vv.y + (double)vv.z*vv.z + (double)vv.w*vv.w;
  }
  kn2d[bh*TT + t] = s2; kn2f[bh*TT + t] = (float)s2;
  red[tid] = s; __syncthreads();
  for(int o = 128; o > 0; o >>= 1){ if(tid < o) red[tid] = fmax(red[tid], red[tid+o]); __syncthreads(); }
  if(tid == 0) qmaxp[bh*16 + chunk] = red[0];
  __syncthreads();
  red[tid] = s2; __syncthreads();
  for(int o = 128; o > 0; o >>= 1){ if(tid < o) red[tid] = fmax(red[tid], red[tid+o]); __syncthreads(); }
  if(tid == 0) kmaxp[bh*16 + chunk] = red[0];
}

__global__ void k_mqk(const double* __restrict__ qmaxp, const double* __restrict__ kmaxp,
                      double* __restrict__ mqk2){
  int bh = blockIdx.x;
  if(threadIdx.x == 0){
    double mq = -1e300, mk = -1e300;
    for(int i = 0; i < 16; i++){ mq = fmax(mq, qmaxp[bh*16 + i]); mk = fmax(mk, kmaxp[bh*16 + i]); }
    mqk2[bh] = mq + mk;
  }
}

// ---------------- K2: E2LSH hashes (float64) ----------------
__global__ void k_hash(const float* __restrict__ q, const float* __restrict__ kk,
                       const float* __restrict__ alpha, const float* __restrict__ beta,
                       const double* __restrict__ qn2d, const double* __restrict__ kn2d,
                       const double* __restrict__ mqk2,
                       double* __restrict__ qh, double* __restrict__ kh){
  __shared__ double al[264];
  __shared__ double be[4];
  int tid = threadIdx.x;
  for(int i = tid; i < 264; i += 256) al[i] = (double)alpha[i];
  if(tid < 4) be[tid] = (double)beta[tid];
  __syncthreads();
  int gid = blockIdx.x*256 + tid;
  int side = gid >> 16; int r = gid & 65535;
  int bh = r >> 12, t = r & 4095;
  int b = bh >> 3, hh = bh & 7;
  const float* x = (side ? kk : q) + (((size_t)(b*TT + t)*TH) + hh)*TE;
  const float4* xr = (const float4*)x;
  double a0 = 0.0, a1 = 0.0, a2 = 0.0, a3 = 0.0;
  #pragma unroll
  for(int c = 0; c < 16; c++){
    float4 vv = xr[c];
    const double* a = al + c*16;
    a0 += (double)vv.x*a[0]  + (double)vv.y*a[4]  + (double)vv.z*a[8]  + (double)vv.w*a[12];
    a1 += (double)vv.x*a[1]  + (double)vv.y*a[5]  + (double)vv.z*a[9]  + (double)vv.w*a[13];
    a2 += (double)vv.x*a[2]  + (double)vv.y*a[6]  + (double)vv.z*a[10] + (double)vv.w*a[14];
    a3 += (double)vv.x*a[3]  + (double)vv.y*a[7]  + (double)vv.z*a[11] + (double)vv.w*a[15];
  }
  double n2  = (side ? kn2d : qn2d)[bh*TT + t];
  double ext = sqrt(fmax(mqk2[bh] - n2, 0.0));
  int ec = side ? 65 : 64;
  double* dst = side ? kh : qh;
  dst[((size_t)0*TBH + bh)*TT + t] = a0 + ext*al[ec*4 + 0] + be[0];
  dst[((size_t)1*TBH + bh)*TT + t] = a1 + ext*al[ec*4 + 1] + be[1];
  dst[((size_t)2*TBH + bh)*TT + t] = a2 + ext*al[ec*4 + 2] + be[2];
  dst[((size_t)3*TBH + bh)*TT + t] = a3 + ext*al[ec*4 + 3] + be[3];
}

// ---------------- K3: stable argsort via bitonic on doubles (1024 thr) ----------------
__global__ void k_sort(const double* __restrict__ qh, const double* __restrict__ kh,
                       int* __restrict__ qpos, int* __restrict__ kpos,
                       int* __restrict__ qrev, int* __restrict__ krev){
  __shared__ double v[4096];
  __shared__ int    ix[4096];
  int blk = blockIdx.x; int side = blk >> 6; int hb = blk & 63;
  const double* src = (side ? kh : qh) + (size_t)hb*TT;
  int tid = threadIdx.x;
  for(int i = tid; i < 4096; i += 1024){ v[i] = src[i]; ix[i] = i; }
  __syncthreads();
  for(int k = 2; k <= 4096; k <<= 1){
    for(int j = k >> 1; j > 0; j >>= 1){
      for(int i = tid; i < 4096; i += 1024){
        int l = i ^ j;
        if(l > i){
          double va = v[i], vb = v[l]; int ia = ix[i], ib = ix[l];
          bool gt  = (va > vb) || (va == vb && ia > ib);
          bool asc = ((i & k) == 0);
          if(gt == asc){ v[i] = vb; v[l] = va; ix[i] = ib; ix[l] = ia; }
        }
      }
      __syncthreads();
    }
  }
  int* pos = (side ? kpos : qpos) + (size_t)hb*TT;
  int* rev = (side ? krev : qrev) + (size_t)hb*TT;
  for(int i = tid; i < 4096; i += 1024){ int id = ix[i]; pos[i] = id; rev[id] = i; }
}

// ---------------- K4: dash GEMM (both sides) -> dash[bh][t][m] ----------------
__launch_bounds__(256, 2)
__global__ void k_dash(const float* __restrict__ q, const float* __restrict__ kk,
                       const float* __restrict__ proj,
                       const float* __restrict__ qn2f, const float* __restrict__ kn2f,
                       float* __restrict__ qdash, float* __restrict__ kdash){
  __shared__ __align__(16) float pjL[64*260];
  __shared__ __align__(16) float x_l[64*68];
  __shared__ float x_n[64];
  int tid = threadIdx.x;
  int bx = blockIdx.x;
  int side = bx >> 10; int r = bx & 1023; int bh = r >> 6; int ch = r & 63;
  int b = bh >> 3, hh = bh & 7, t0 = ch*64;
  const float* x  = side ? kk   : q;
  const float* n2 = side ? kn2f : qn2f;
  float* outp     = side ? kdash : qdash;

  #pragma unroll 8
  for(int it = 0; it < 64; it++){
    int idx = it*256 + tid;
    pjL[(idx & 63)*260 + (idx >> 6)] = proj[idx];
  }
  {
    int rr = tid >> 2, c = tid & 3;
    const float4* src = (const float4*)(x + (((size_t)(b*TT + t0 + rr)*TH) + hh)*TE);
    float4* dst = (float4*)(x_l + rr*68);
    #pragma unroll
    for(int i = 0; i < 4; i++) dst[c*4 + i] = src[c*4 + i];
  }
  if(tid < 64) x_n[tid] = n2[bh*TT + t0 + tid];
  __syncthreads();

  int ml = (tid & 15)*4;
  int tb = tid >> 4;
  float4 acc[4][4];
  #pragma unroll
  for(int tt = 0; tt < 4; tt++)
    #pragma unroll
    for(int g = 0; g < 4; g++) acc[tt][g] = make_float4(0.f,0.f,0.f,0.f);

  #pragma unroll 4
  for(int k4 = 0; k4 < 16; k4++){
    float4 xv[4];
    #pragma unroll
    for(int tt = 0; tt < 4; tt++)
      xv[tt] = *((const float4*)(x_l + (tb + 16*tt)*68 + k4*4));
    #pragma unroll
    for(int kk4 = 0; kk4 < 4; kk4++){
      int krow = k4*4 + kk4;
      #pragma unroll
      for(int g = 0; g < 4; g++){
        float4 pv = *((const float4*)(pjL + krow*260 + ml + 64*g));
        #pragma unroll
        for(int tt = 0; tt < 4; tt++){
          float xs = (kk4 == 0) ? xv[tt].x : (kk4 == 1) ? xv[tt].y : (kk4 == 2) ? xv[tt].z : xv[tt].w;
          acc[tt][g].x = fmaf(xs, pv.x, acc[tt][g].x);
          acc[tt][g].y = fmaf(xs, pv.y, acc[tt][g].y);
          acc[tt][g].z = fmaf(xs, pv.z, acc[tt][g].z);
          acc[tt][g].w = fmaf(xs, pv.w, acc[tt][g].w);
        }
      }
    }
  }
  #pragma unroll
  for(int tt = 0; tt < 4; tt++){
    int t_r = tb + 16*tt;
    float diag = 0.5f*C_TEMP*x_n[t_r];
    size_t rowbase = ((size_t)bh*TT + t0 + t_r)*256;
    #pragma unroll
    for(int g = 0; g < 4; g++){
      float4 a = acc[tt][g];
      float4 dd;
      dd.x = fmaf(C_DN, a.x, -diag); dd.y = fmaf(C_DN, a.y, -diag);
      dd.z = fmaf(C_DN, a.z, -diag); dd.w = fmaf(C_DN, a.w, -diag);
      *((float4*)(outp + rowbase + ml + 64*g)) = dd;
    }
  }
}

// ---------------- K4b: max over dashK chunks -> klsp ----------------
__global__ void k_klsmax(const float* __restrict__ kdash, float* __restrict__ klsp){
  __shared__ float wr[4];
  int tid = threadIdx.x;
  int bx = blockIdx.x; int bh = bx >> 7, ch = bx & 127;
  const float4* src = (const float4*)(kdash + ((size_t)bh << 20)) + ch*2048;
  float mx = -1e30f;
  #pragma unroll
  for(int i = 0; i < 8; i++){
    float4 vv = src[i*256 + tid];
    mx = fmaxf(mx, fmaxf(fmaxf(vv.x, vv.y), fmaxf(vv.z, vv.w)));
  }
  #pragma unroll
  for(int o = 32; o > 0; o >>= 1) mx = fmaxf(mx, __shfl_xor(mx, o, 64));
  if((tid & 63) == 0) wr[tid >> 6] = mx;
  __syncthreads();
  if(tid == 0) klsp[bh*128 + ch] = fmaxf(fmaxf(wr[0], wr[1]), fmaxf(wr[2], wr[3]));
}

__global__ void k_klsred(const float* __restrict__ klsp, float* __restrict__ kls){
  __shared__ float red[2];
  int bh = blockIdx.x, tid = threadIdx.x;
  float v = klsp[bh*128 + tid];
  #pragma unroll
  for(int o = 32; o > 0; o >>= 1) v = fmaxf(v, __shfl_xor(v, o, 64));
  if((tid & 63) == 0) red[tid >> 6] = v;
  __syncthreads();
  if(tid == 0) kls[bh] = fmaxf(red[0], red[1]);
}

// ---------------- K4c: kp = exp(dashK - kls)*ratio, in place ----------------
__global__ void k_expk(float* __restrict__ kp, const float* __restrict__ kls){
  int tid = threadIdx.x; int blk = blockIdx.x;
  float4* p = (float4*)kp;
  size_t base = (size_t)blk*2048;
  float stab = kls[blk >> 7];
  #pragma unroll
  for(int i = 0; i < 8; i++){
    size_t ix = base + i*256 + tid;
    float4 vv = p[ix];
    vv.x = __expf(vv.x - stab)*C_RATIO; vv.y = __expf(vv.y - stab)*C_RATIO;
    vv.z = __expf(vv.z - stab)*C_RATIO; vv.w = __expf(vv.w - stab)*C_RATIO;
    p[ix] = vv;
  }
}

// ---------------- K4d: qp = exp(dashQ - rowmax)*ratio in place, pls = rowmax ----------------
__global__ void k_expq(float* __restrict__ qp, float* __restrict__ pls){
  int tid = threadIdx.x, wid = tid >> 6, lane = tid & 63;
  int row = blockIdx.x*4 + wid;
  float4* p = (float4*)(qp + (size_t)row*256);
  float4 vv = p[lane];
  float mr = fmaxf(fmaxf(vv.x, vv.y), fmaxf(vv.z, vv.w));
  #pragma unroll
  for(int o = 32; o > 0; o >>= 1) mr = fmaxf(mr, __shfl_xor(mr, o, 64));
  float4 rr;
  rr.x = __expf(vv.x - mr)*C_RATIO; rr.y = __expf(vv.y - mr)*C_RATIO;
  rr.z = __expf(vv.z - mr)*C_RATIO; rr.w = __expf(vv.w - mr)*C_RATIO;
  p[lane] = rr;
  if(lane == 0) pls[row] = mr;
}

// ---------------- K5: kv partials over s-chunks, then reduce ----------------
__global__ void k_kv2(const float* __restrict__ kp, const float* __restrict__ v,
                      float* __restrict__ kvp, float* __restrict__ ksump){
  int bx = blockIdx.x; int sc = bx >> 7; int rem = bx & 127; int bh = rem >> 3; int mt = rem & 7;
  int tid = threadIdx.x; int g = tid >> 6, d = tid & 63;
  int b = bh >> 3, hh = bh & 7; int m0 = mt*32;
  float a[8], sa[8];
  #pragma unroll
  for(int j = 0; j < 8; j++){ a[j] = 0.f; sa[j] = 0.f; }
  const float* kpb = kp + (size_t)bh*TT*256 + m0 + g;
  const float* vb  = v + (size_t)b*TT*TH*TE + hh*TE + d;
  int s0 = sc*1024;
  #pragma unroll 4
  for(int s = s0; s < s0 + 1024; s++){
    float vv = vb[(size_t)s*512];
    const float* kr = kpb + (size_t)s*256;
    #pragma unroll
    for(int j = 0; j < 8; j++){
      float kj = kr[4*j];
      a[j] = fmaf(kj, vv, a[j]); sa[j] += kj;
    }
  }
  #pragma unroll
  for(int j = 0; j < 8; j++){
    int m = m0 + g + 4*j;
    kvp[(((size_t)sc*16 + bh)*256 + m)*64 + d] = a[j];
    if(d == 0) ksump[((size_t)sc*16 + bh)*256 + m] = sa[j];
  }
}

__global__ void k_kvred(const float* __restrict__ kvp, const float* __restrict__ ksump,
                        float* __restrict__ kv, float* __restrict__ ksum){
  int bx = blockIdx.x, tid = threadIdx.x;
  if(bx < 256){
    size_t i = (size_t)bx*1024 + tid*4;
    float4 s = make_float4(0.f,0.f,0.f,0.f);
    #pragma unroll
    for(int sc = 0; sc < 4; sc++){
      float4 p = *((const float4*)(kvp + (size_t)sc*262144 + i));
      s.x += p.x; s.y += p.y; s.z += p.z; s.w += p.w;
    }
    *((float4*)(kv + i)) = s;
  } else {
    for(int m = tid; m < 4096; m += 256){
      float s = 0.f;
      #pragma unroll
      for(int sc = 0; sc < 4; sc++) s += ksump[sc*4096 + m];
      ksum[m] = s;
    }
  }
}

// ---------------- K6: per-bucket attention, MFMA split-bf16 ----------------
// LDS: bufA(34816) = Q / QP-chunk / D-half; bufB(34816) = K / KP-chunk / V^T.
// Row layout (A/B frags, 16x16x32 bf16): 64 hi | 64 lo | 8 pad shorts = 272 B.
// V^T: 64 rows x (128 hi | 128 lo | 8 pad) = 528 B.
__launch_bounds__(256, 2)
__global__ void k_bucket(const float* __restrict__ q, const float* __restrict__ kk, const float* __restrict__ v,
                         const float* __restrict__ qp, const float* __restrict__ kp,
                         const int* __restrict__ qpos, const int* __restrict__ kpos,
                         const int* __restrict__ qrev, const int* __restrict__ krev,
                         const float* __restrict__ pls, const float* __restrict__ kls,
                         const float* __restrict__ qn2f, const float* __restrict__ kn2f,
                         float* __restrict__ o_t, float* __restrict__ lse_t, float* __restrict__ dsum_t){
  __shared__ __align__(16) char smem[73232];
  constexpr int OFS_B = 34816;
  int* qidxL   = (int*)(smem + 69632);
  int* kidxL   = (int*)(smem + 70144);
  int* qbpL    = (int*)(smem + 70656);
  int* kbpL    = (int*)(smem + 71168);
  float* lseL  = (float*)(smem + 71680);
  float* pfacL = (float*)(smem + 72192);
  float* kn2L  = (float*)(smem + 72704);
  float* kmaxP = (float*)(smem + 73216);

  int tid = threadIdx.x;
  int w = tid >> 6, lane = tid & 63, l15 = lane & 15, quad = lane >> 4;
  int bx = blockIdx.x; int n = bx & 31, bh = (bx >> 5) & 15, h = bx >> 9;
  int b = bh >> 3, hh = bh & 7;

  if(tid < 128){
    int tk = kpos[((size_t)h*TBH + bh)*TT + n*128 + tid];
    kidxL[tid] = tk;
    int pk = 0;
    #pragma unroll
    for(int h3 = 0; h3 < 4; h3++){ int rv = krev[((size_t)h3*TBH + bh)*TT + tk]; pk |= (rv >> 7) << (8*h3); }
    kbpL[tid] = pk;
    kn2L[tid] = kn2f[(size_t)bh*TT + tk];
    int tq = qpos[((size_t)h*TBH + bh)*TT + n*128 + tid];
    qidxL[tid] = tq;
    int pq = 0;
    #pragma unroll
    for(int h3 = 0; h3 < 4; h3++){ int rv = qrev[((size_t)h3*TBH + bh)*TT + tq]; pq |= (rv >> 7) << (8*h3); }
    qbpL[tid] = pq;
  }
  __syncthreads();
  if(tid < 64){
    float m = fmaxf(kn2L[tid], kn2L[tid + 64]);
    #pragma unroll
    for(int o = 32; o > 0; o >>= 1) m = fmaxf(m, __shfl_xor(m, o, 64));
    if(tid == 0) kmaxP[0] = m;
  }
  {  // stage Q into bufA, K into bufB (bf16 hi/lo)
    int r = tid >> 1, hf = tid & 1;
    const float4* qs = (const float4*)(q  + (((size_t)(b*TT + qidxL[r])*TH) + hh)*TE) + hf*8;
    const float4* ks = (const float4*)(kk + (((size_t)(b*TT + kidxL[r])*TH) + hh)*TE) + hf*8;
    stage64(smem + r*272, qs, hf);
    stage64(smem + OFS_B + r*272, ks, hf);
  }
  __syncthreads();
  if(tid < 128){  // per-row stabilizer (Cauchy-Schwarz UB) + pfac
    int tq = qidxL[tid];
    float plsv = pls[(size_t)bh*TT + tq] + kls[bh];
    float lse = fmaxf(plsv, C_TEMP * sqrtf(qn2f[(size_t)bh*TT + tq] * kmaxP[0]));
    lseL[tid] = lse;
    pfacL[tid] = __expf(plsv - lse);
  }

  f32x4 acc_s[2][8], acc_p[2][8];
  #pragma unroll
  for(int mt = 0; mt < 2; mt++)
    #pragma unroll
    for(int nt = 0; nt < 8; nt++){
      acc_s[mt][nt] = (f32x4){0.f,0.f,0.f,0.f};
      acc_p[mt][nt] = (f32x4){0.f,0.f,0.f,0.f};
    }

  {  // S = Q K^T (K=64, split-3)
    bf16x8 ahi[2][2], alo[2][2];
    #pragma unroll
    for(int mt = 0; mt < 2; mt++)
      #pragma unroll
      for(int ks = 0; ks < 2; ks++){
        const char* ap = smem + (32*w + 16*mt + l15)*272 + 64*ks + 16*quad;
        ahi[mt][ks] = *((const bf16x8*)ap);
        alo[mt][ks] = *((const bf16x8*)(ap + 128));
      }
    #pragma unroll
    for(int nt = 0; nt < 8; nt++){
      #pragma unroll
      for(int ks = 0; ks < 2; ks++){
        const char* bp = smem + OFS_B + (16*nt + l15)*272 + 64*ks + 16*quad;
        bf16x8 bhi = *((const bf16x8*)bp);
        bf16x8 blo = *((const bf16x8*)(bp + 128));
        #pragma unroll
        for(int mt = 0; mt < 2; mt++){
          acc_s[mt][nt] = __builtin_amdgcn_mfma_f32_16x16x32_bf16(ahi[mt][ks], bhi, acc_s[mt][nt], 0, 0, 0);
          acc_s[mt][nt] = __builtin_amdgcn_mfma_f32_16x16x32_bf16(ahi[mt][ks], blo, acc_s[mt][nt], 0, 0, 0);
          acc_s[mt][nt] = __builtin_amdgcn_mfma_f32_16x16x32_bf16(alo[mt][ks], bhi, acc_s[mt][nt], 0, 0, 0);
        }
      }
    }
  }
  __syncthreads();

  // DP = QP KP^T (K=256 in 4 chunks of 64, split-3)
  for(int c = 0; c < 4; c++){
    { int r = tid >> 1, hf = tid & 1;
      const float4* qs = (const float4*)(qp + ((size_t)bh*TT + qidxL[r])*256 + c*64) + hf*8;
      const float4* ks = (const float4*)(kp + ((size_t)bh*TT + kidxL[r])*256 + c*64) + hf*8;
      stage64(smem + r*272, qs, hf);
      stage64(smem + OFS_B + r*272, ks, hf);
    }
    __syncthreads();
    bf16x8 ahi[2][2], alo[2][2];
    #pragma unroll
    for(int mt = 0; mt < 2; mt++)
      #pragma unroll
      for(int ks = 0; ks < 2; ks++){
        const char* ap = smem + (32*w + 16*mt + l15)*272 + 64*ks + 16*quad;
        ahi[mt][ks] = *((const bf16x8*)ap);
        alo[mt][ks] = *((const bf16x8*)(ap + 128));
      }
    #pragma unroll
    for(int nt = 0; nt < 8; nt++){
      #pragma unroll
      for(int ks = 0; ks < 2; ks++){
        const char* bp = smem + OFS_B + (16*nt + l15)*272 + 64*ks + 16*quad;
        bf16x8 bhi = *((const bf16x8*)bp);
        bf16x8 blo = *((const bf16x8*)(bp + 128));
        #pragma unroll
        for(int mt = 0; mt < 2; mt++){
          acc_p[mt][nt] = __builtin_amdgcn_mfma_f32_16x16x32_bf16(ahi[mt][ks], bhi, acc_p[mt][nt], 0, 0, 0);
          acc_p[mt][nt] = __builtin_amdgcn_mfma_f32_16x16x32_bf16(ahi[mt][ks], blo, acc_p[mt][nt], 0, 0, 0);
          acc_p[mt][nt] = __builtin_amdgcn_mfma_f32_16x16x32_bf16(alo[mt][ks], bhi, acc_p[mt][nt], 0, 0, 0);
        }
      }
    }
    __syncthreads();
  }

  {  // stage V^T into bufB (bf16 hi/lo, transposed)
    int j = tid >> 1, hc = tid & 1;
    const float4* vs = (const float4*)(v + (((size_t)(b*TT + kidxL[j])*TH) + hh)*TE) + hc*8;
    #pragma unroll
    for(int x = 0; x < 8; x++){
      float4 vv = vs[x];
      int c0 = hc*32 + 4*x;
      float vals[4] = {vv.x, vv.y, vv.z, vv.w};
      #pragma unroll
      for(int i = 0; i < 4; i++){
        uint16_t hi = f2bf(vals[i]);
        float lo = vals[i] - bf2f(hi);
        *((uint16_t*)(smem + OFS_B + (c0 + i)*528 + 2*j)) = hi;
        *((uint16_t*)(smem + OFS_B + (c0 + i)*528 + 256 + 2*j)) = f2bf(lo);
      }
    }
  }
  int qbp_r[8]; float lse_r[8], pfac_r[8], dsump[8]; int kbp_c[8];
  #pragma unroll
  for(int i = 0; i < 8; i++){
    int r = 32*w + 16*(i >> 2) + 4*quad + (i & 3);
    qbp_r[i] = qbpL[r]; lse_r[i] = lseL[r]; pfac_r[i] = pfacL[r]; dsump[i] = 0.f;
  }
  #pragma unroll
  for(int nt = 0; nt < 8; nt++) kbp_c[nt] = kbpL[l15 + 16*nt];
  __syncthreads();

  // D (elementwise in C-layout regs) -> LDS bf16 hi/lo -> O += D V (two col-halves)
  f32x4 acc_o[2][4];
  #pragma unroll
  for(int mt = 0; mt < 2; mt++)
    #pragma unroll
    for(int nv = 0; nv < 4; nv++) acc_o[mt][nv] = (f32x4){0.f,0.f,0.f,0.f};

  #pragma unroll
  for(int hv = 0; hv < 2; hv++){
    #pragma unroll
    for(int nt = 0; nt < 4; nt++){
      int ntg = 4*hv + nt;
      #pragma unroll
      for(int mt = 0; mt < 2; mt++){
        f32x4 s4 = acc_s[mt][ntg], p4 = acc_p[mt][ntg];
        #pragma unroll
        for(int e = 0; e < 4; e++){
          int i = mt*4 + e;
          int du = dupc((uint32_t)(qbp_r[i] ^ kbp_c[ntg]));
          float ein  = __expf(fmaf(C_TEMP, s4[e], -lndup(du)) - lse_r[i]);
          float dots = fmaf(-p4[e]*rcpdup(du), pfac_r[i], ein);
          dsump[i] += dots;
          int row = 32*w + 16*mt + 4*quad + e;
          int colL = l15 + 16*nt;
          uint16_t hi = f2bf(dots);
          float lo = dots - bf2f(hi);
          *((uint16_t*)(smem + row*272 + 2*colL)) = hi;
          *((uint16_t*)(smem + row*272 + 128 + 2*colL)) = f2bf(lo);
        }
      }
    }
    // O MFMAs for this k-half (each wave reads only its own D rows -> no barrier needed)
    bf16x8 dhi[2][2], dlo[2][2];
    #pragma unroll
    for(int mt = 0; mt < 2; mt++)
      #pragma unroll
      for(int ks = 0; ks < 2; ks++){
        const char* ap = smem + (32*w + 16*mt + l15)*272 + 64*ks + 16*quad;
        dhi[mt][ks] = *((const bf16x8*)ap);
        dlo[mt][ks] = *((const bf16x8*)(ap + 128));
      }
    #pragma unroll
    for(int nv = 0; nv < 4; nv++){
      #pragma unroll
      for(int ks = 0; ks < 2; ks++){
        const char* bp = smem + OFS_B + (16*nv + l15)*528 + 128*hv + 64*ks + 16*quad;
        bf16x8 vhi = *((const bf16x8*)bp);
        bf16x8 vlo = *((const bf16x8*)(bp + 256));
        #pragma unroll
        for(int mt = 0; mt < 2; mt++){
          acc_o[mt][nv] = __builtin_amdgcn_mfma_f32_16x16x32_bf16(dhi[mt][ks], vhi, acc_o[mt][nv], 0, 0, 0);
          acc_o[mt][nv] = __builtin_amdgcn_mfma_f32_16x16x32_bf16(dhi[mt][ks], vlo, acc_o[mt][nv], 0, 0, 0);
          acc_o[mt][nv] = __builtin_amdgcn_mfma_f32_16x16x32_bf16(dlo[mt][ks], vhi, acc_o[mt][nv], 0, 0, 0);
        }
      }
    }
  }

  // epilogue
  #pragma unroll
  for(int i = 0; i < 8; i++){
    float s = dsump[i];
    s += __shfl_xor(s, 1, 64); s += __shfl_xor(s, 2, 64);
    s += __shfl_xor(s, 4, 64); s += __shfl_xor(s, 8, 64);
    dsump[i] = s;
  }
  size_t obase = ((size_t)h*TBH + bh)*TT;
  if(l15 == 0){
    #pragma unroll
    for(int i = 0; i < 8; i++){
      int r = 32*w + 16*(i >> 2) + 4*quad + (i & 3);
      int tq = qidxL[r];
      lse_t [obase + tq] = lse_r[i];
      dsum_t[obase + tq] = dsump[i];
    }
  }
  #pragma unroll
  for(int mt = 0; mt < 2; mt++){
    #pragma unroll
    for(int e = 0; e < 4; e++){
      int r = 32*w + 16*mt + 4*quad + e;
      int tq = qidxL[r];
      float* orow = o_t + (obase + tq)*64;
      #pragma unroll
      for(int nv = 0; nv < 4; nv++) orow[l15 + 16*nv] = acc_o[mt][nv][e];
    }
  }
}

// ---------------- K7: combine hash rounds + performer term ----------------
__global__ void k_final(const float* __restrict__ qp, const float* __restrict__ kv,
                        const float* __restrict__ ksum, const float* __restrict__ o_t,
                        const float* __restrict__ lse_t, const float* __restrict__ dsum_t,
                        const float* __restrict__ pls, const float* __restrict__ kls,
                        float* __restrict__ out){
  __shared__ float kv_l[256*64];
  int tid = threadIdx.x;
  int bx = blockIdx.x; int chunk = bx & 15; int bh = bx >> 4;
  for(int idx = tid; idx < 16384; idx += 256) kv_l[idx] = kv[(size_t)bh*16384 + idx];
  __syncthreads();
  int wid = tid >> 6, lane = tid & 63;
  int b = bh >> 3, hh = bh & 7;
  float klsv = kls[bh];
  int t0 = chunk*256;
  for(int r = wid; r < 256; r += 4){
    int t = t0 + r;
    const float* qr = qp + ((size_t)bh*TT + t)*256;
    float q0 = qr[lane], q1 = qr[64 + lane], q2 = qr[128 + lane], q3 = qr[192 + lane];
    float qkv = 0.f;
    #pragma unroll 8
    for(int mm = 0; mm < 64; mm++){
      float c0 = __shfl(q0, mm, 64), c1 = __shfl(q1, mm, 64), c2 = __shfl(q2, mm, 64), c3 = __shfl(q3, mm, 64);
      qkv = fmaf(c0, kv_l[(      mm)*64 + lane], qkv);
      qkv = fmaf(c1, kv_l[( 64 + mm)*64 + lane], qkv);
      qkv = fmaf(c2, kv_l[(128 + mm)*64 + lane], qkv);
      qkv = fmaf(c3, kv_l[(192 + mm)*64 + lane], qkv);
    }
    float p1 = q0*ksum[bh*256 + lane] + q1*ksum[bh*256 + 64 + lane]
             + q2*ksum[bh*256 + 128 + lane] + q3*ksum[bh*256 + 192 + lane];
    #pragma unroll
    for(int o = 32; o > 0; o >>= 1) p1 += __shfl_xor(p1, o, 64);
    float l0 = lse_t[((size_t)0*TBH + bh)*TT + t], l1 = lse_t[((size_t)1*TBH + bh)*TT + t];
    float l2 = lse_t[((size_t)2*TBH + bh)*TT + t], l3 = lse_t[((size_t)3*TBH + bh)*TT + t];
    float M = fmaxf(fmaxf(l0, l1), fmaxf(l2, l3));
    float e0 = __expf(l0 - M), e1 = __expf(l1 - M), e2 = __expf(l2 - M), e3 = __expf(l3 - M);
    float rs = 1.f / (e0 + e1 + e2 + e3);
    float pr0 = e0*rs, pr1 = e1*rs, pr2 = e2*rs, pr3 = e3*rs;
    float psc = __expf(pls[bh*TT + t] + klsv - M)*rs;
    float outl = 0.f, nrm = 0.f;
    outl = fmaf(o_t[(((size_t)0*TBH + bh)*TT + t)*64 + lane], pr0, outl);
    outl = fmaf(o_t[(((size_t)1*TBH + bh)*TT + t)*64 + lane], pr1, outl);
    outl = fmaf(o_t[(((size_t)2*TBH + bh)*TT + t)*64 + lane], pr2, outl);
    outl = fmaf(o_t[(((size_t)3*TBH + bh)*TT + t)*64 + lane], pr3, outl);
    nrm  = fmaf(dsum_t[((size_t)0*TBH + bh)*TT + t], pr0, nrm);
    nrm  = fmaf(dsum_t[((size_t)1*TBH + bh)*TT + t], pr1, nrm);
    nrm  = fmaf(dsum_t[((size_t)2*TBH + bh)*TT + t], pr2, nrm);
    nrm  = fmaf(dsum_t[((size_t)3*TBH + bh)*TT + t], pr3, nrm);
    nrm  = fmaf(p1, psc, nrm);
    float res = (outl + qkv*psc) / fmaxf(nrm, 1e-6f);
    out[((size_t)(b*TT + t)*TH + hh)*64 + lane] = res;
  }
}

// sentinel: signals ws_size-too-small distinctly from a numeric bug
__global__ void k_sentinel(float* __restrict__ out, int n){
  int i = blockIdx.x*256 + threadIdx.x;
  if(i < n) out[i] = 12345.0f;
}

extern "C" void kernel_launch(void* const* d_in, const int* in_sizes, int n_in,
                              void* d_out, int out_size, void* d_ws, size_t ws_size,
                              hipStream_t stream){
  const float* q     = (const float*)d_in[0];
  const float* k     = (const float*)d_in[1];
  const float* v     = (const float*)d_in[2];
  const float* proj  = (const float*)d_in[3];
  const float* alpha = (const float*)d_in[4];
  const float* beta  = (const float*)d_in[5];
  float* out = (float*)d_out;
  char* ws = (char*)d_ws;

  if(ws_size < WS_NEED){
    k_sentinel<<<dim3((out_size + 255)/256), dim3(256), 0, stream>>>(out, out_size);
    return;
  }

  float*  qn2f  = (float*) (ws + OFF_QN2F);
  float*  kn2f  = (float*) (ws + OFF_KN2F);
  double* qn2d  = (double*)(ws + OFF_QN2D);
  double* kn2d  = (double*)(ws + OFF_KN2D);
  double* mqk2  = (double*)(ws + OFF_MQK2);
  double* qmaxp = (double*)(ws + OFF_QMAXP);
  double* kmaxp = (double*)(ws + OFF_KMAXP);
  double* qh    = (double*)(ws + OFF_QH);
  double* kh    = (double*)(ws + OFF_KH);
  int*   qpos   = (int*)  (ws + OFF_QPOS);
  int*   kpos   = (int*)  (ws + OFF_KPOS);
  int*   qrev   = (int*)  (ws + OFF_QREV);
  int*   krev   = (int*)  (ws + OFF_KREV);
  float* klsp   = (float*)(ws + OFF_KLSP);
  float* kls    = (float*)(ws + OFF_KLS);
  float* qp     = (float*)(ws + OFF_QP);   // doubles as dashQ
  float* kp     = (float*)(ws + OFF_KP);   // doubles as dashK
  float* pls    = (float*)(ws + OFF_PLS);
  float* ksum   = (float*)(ws + OFF_KSUM);
  float* kvv    = (float*)(ws + OFF_KV);
  float* o_t    = (float*)(ws + OFF_OT);
  float* lse_t  = (float*)(ws + OFF_LSET);
  float* dsum_t = (float*)(ws + OFF_DSUM);
  float* kvp    = (float*)(ws + OFF_KVP);  // overlays dead qn2d/kn2d/qh/kh
  float* ksump  = (float*)(ws + OFF_KSP);

  k_norms2<<<dim3(256),   dim3(256),  0, stream>>>(q, k, qn2f, kn2f, qn2d, kn2d, qmaxp, kmaxp);
  k_mqk   <<<dim3(16),    dim3(64),   0, stream>>>(qmaxp, kmaxp, mqk2);
  k_hash  <<<dim3(512),   dim3(256),  0, stream>>>(q, k, alpha, beta, qn2d, kn2d, mqk2, qh, kh);
  k_sort  <<<dim3(128),   dim3(1024), 0, stream>>>(qh, kh, qpos, kpos, qrev, krev);
  k_dash  <<<dim3(2048),  dim3(256),  0, stream>>>(q, k, proj, qn2f, kn2f, qp, kp);
  k_klsmax<<<dim3(2048),  dim3(256),  0, stream>>>(kp, klsp);
  k_klsred<<<dim3(16),    dim3(128),  0, stream>>>(klsp, kls);
  k_expk  <<<dim3(2048),  dim3(256),  0, stream>>>(kp, kls);
  k_expq  <<<dim3(16384), dim3(256),  0, stream>>>(qp, pls);
  k_kv2   <<<dim3(512),   dim3(256),  0, stream>>>(kp, v, kvp, ksump);
  k_kvred <<<dim3(257),   dim3(256),  0, stream>>>(kvp, ksump, kvv, ksum);
  k_bucket<<<dim3(2048),  dim3(256),  0, stream>>>(q, k, v, qp, kp, qpos, kpos, qrev, krev, pls, kls, qn2f, kn2f, o_t, lse_t, dsum_t);
  k_final <<<dim3(256),   dim3(256),  0, stream>>>(qp, kvv, ksum, o_t, lse_t, dsum_t, pls, kls, out);
}

// Round 6
// 745.250 us; speedup vs baseline: 6.2144x; 1.3414x over previous
//
#include <hip/hip_runtime.h>
#include <stdint.h>
#include <math.h>

#define DEVI __device__ __forceinline__

// Problem constants (B,T,H,E fixed by the reference setup)
constexpr int TB  = 2;
constexpr int TT  = 4096;
constexpr int TH  = 8;
constexpr int TE  = 64;
constexpr int TBH = 16;   // B*H
constexpr int TM  = 256;  // performer features
constexpr int TNH = 4;    // hash rounds
constexpr float C_TEMP  = 0.125f;                 // 1/sqrt(E)
constexpr float C_DN    = 0.35355339059327373f;   // sqrt(temp)
constexpr float C_RATIO = 0.0625f;                // M^-0.5

typedef __attribute__((ext_vector_type(8))) short bf16x8;
typedef __attribute__((ext_vector_type(4))) float f32x4;

// ---------------- workspace layout ----------------
constexpr size_t algn(size_t x){ return (x + 255) & ~(size_t)255; }
constexpr size_t OFF_QN2F = 0;
constexpr size_t OFF_KN2F = algn(OFF_QN2F + (size_t)TBH*TT*4);
constexpr size_t OFF_QN2D = algn(OFF_KN2F + (size_t)TBH*TT*4);
constexpr size_t OFF_KN2D = algn(OFF_QN2D + (size_t)TBH*TT*8);
constexpr size_t OFF_MQK2 = algn(OFF_KN2D + (size_t)TBH*TT*8);
constexpr size_t OFF_QMAXP= algn(OFF_MQK2 + (size_t)TBH*8);
constexpr size_t OFF_KMAXP= algn(OFF_QMAXP+ (size_t)TBH*16*8);
constexpr size_t OFF_QH   = algn(OFF_KMAXP+ (size_t)TBH*16*8);
constexpr size_t OFF_KH   = algn(OFF_QH   + (size_t)TNH*TBH*TT*8);
constexpr size_t OFF_QPOS = algn(OFF_KH   + (size_t)TNH*TBH*TT*8);
constexpr size_t OFF_KPOS = algn(OFF_QPOS + (size_t)TNH*TBH*TT*4);
constexpr size_t OFF_QREV = algn(OFF_KPOS + (size_t)TNH*TBH*TT*4);
constexpr size_t OFF_KREV = algn(OFF_QREV + (size_t)TNH*TBH*TT*4);
constexpr size_t OFF_KLSP = algn(OFF_KREV + (size_t)TNH*TBH*TT*4);
constexpr size_t OFF_KLS  = algn(OFF_KLSP + (size_t)TBH*128*4);
constexpr size_t OFF_QP   = algn(OFF_KLS  + (size_t)TBH*4);
constexpr size_t OFF_KP   = algn(OFF_QP   + (size_t)TBH*TT*TM*4);   // fp32, doubles as dashQ
constexpr size_t OFF_PLS  = algn(OFF_KP   + (size_t)TBH*TT*TM*4);   // kp doubles as dashK
constexpr size_t OFF_KSUM = algn(OFF_PLS  + (size_t)TBH*TT*4);
constexpr size_t OFF_KV   = algn(OFF_KSUM + (size_t)TBH*TM*4);
constexpr size_t OFF_OT   = algn(OFF_KV   + (size_t)TBH*TM*TE*4);
constexpr size_t OFF_LSET = algn(OFF_OT   + (size_t)TNH*TBH*TT*TE*4);
constexpr size_t OFF_DSUM = algn(OFF_LSET + (size_t)TNH*TBH*TT*4);
constexpr size_t WS_NEED  = algn(OFF_DSUM + (size_t)TNH*TBH*TT*4);  // ~203 MB
// overlays (dead after k_sort/k_hash): kv partials in qn2d..kh window
constexpr size_t OFF_KVP  = OFF_QN2D;                  // 4 MB (4 x 16 x 256 x 64 f32)
constexpr size_t OFF_KSP  = OFF_KVP + (size_t)4*16*256*64*4;  // 64 KB

// ---------------- helpers ----------------
DEVI float bf2f(uint32_t u16){ uint32_t x = u16 << 16; return __builtin_bit_cast(float, x); }
DEVI uint16_t f2bf(float f){
  uint32_t x = __builtin_bit_cast(uint32_t, f);
  uint32_t r = x + 0x7fffu + ((x >> 16) & 1u);   // RNE
  return (uint16_t)(r >> 16);
}
DEVI int dupc(uint32_t x){
  return (int)((x & 0xffu) == 0) + (int)(((x >> 8) & 0xffu) == 0)
       + (int)(((x >> 16) & 0xffu) == 0) + (int)((x >> 24) == 0);
}
DEVI float lndup(int d){
  return d == 1 ? 0.f : d == 2 ? 0.69314718f : d == 3 ? 1.09861229f : 1.38629436f;
}
DEVI float rcpdup(int d){
  return d == 1 ? 1.f : d == 2 ? 0.5f : d == 3 ? 0.333333343f : 0.25f;
}

// stage 32 floats (half of a 64-wide row) as bf16 hi|lo into a 272B LDS row:
// layout per row: 64 hi shorts | 64 lo shorts | 8 pad shorts
DEVI void stage64(char* rowp, const float4* src8, int hf){
  #pragma unroll
  for(int x = 0; x < 8; x++){
    float4 vv = src8[x];
    uint16_t hx = f2bf(vv.x), hy = f2bf(vv.y), hz = f2bf(vv.z), hw = f2bf(vv.w);
    float lx = vv.x - bf2f(hx), ly = vv.y - bf2f(hy), lz = vv.z - bf2f(hz), lw = vv.w - bf2f(hw);
    uint2 hp = make_uint2((uint32_t)hx | ((uint32_t)hy << 16), (uint32_t)hz | ((uint32_t)hw << 16));
    uint2 lp = make_uint2((uint32_t)f2bf(lx) | ((uint32_t)f2bf(ly) << 16),
                          (uint32_t)f2bf(lz) | ((uint32_t)f2bf(lw) << 16));
    *((uint2*)(rowp + 64*hf + 8*x)) = hp;
    *((uint2*)(rowp + 128 + 64*hf + 8*x)) = lp;
  }
}

// ---------------- K1: row sumsq (f32+f64) + partial max (XBOX+ ext) ----------------
__global__ void k_norms2(const float* __restrict__ q, const float* __restrict__ kk,
                         float* __restrict__ qn2f, float* __restrict__ kn2f,
                         double* __restrict__ qn2d, double* __restrict__ kn2d,
                         double* __restrict__ qmaxp, double* __restrict__ kmaxp){
  __shared__ double red[256];
  int bx = blockIdx.x; int chunk = bx & 15, bh = bx >> 4;
  int tid = threadIdx.x;
  int b = bh >> 3, hh = bh & 7;
  int t = chunk*256 + tid;
  const float4* r1 = (const float4*)(q + (((size_t)(b*TT + t)*TH) + hh)*TE);
  double s = 0.0;
  #pragma unroll
  for(int x = 0; x < 16; x++){
    float4 vv = r1[x];
    s += (double)vv.x*vv.x + (double)vv.y*vv.y + (double)vv.z*vv.z + (double)vv.w*vv.w;
  }
  qn2d[bh*TT + t] = s; qn2f[bh*TT + t] = (float)s;
  const float4* r2 = (const float4*)(kk + (((size_t)(b*TT + t)*TH) + hh)*TE);
  double s2 = 0.0;
  #pragma unroll
  for(int x = 0; x < 16; x++){
    float4 vv = r2[x];
    s2 += (double)vv.x*vv.x + (double)vv.y*vv.y + (double)vv.z*vv.z + (double)vv.w*vv.w;
  }
  kn2d[bh*TT + t] = s2; kn2f[bh*TT + t] = (float)s2;
  red[tid] = s; __syncthreads();
  for(int o = 128; o > 0; o >>= 1){ if(tid < o) red[tid] = fmax(red[tid], red[tid+o]); __syncthreads(); }
  if(tid == 0) qmaxp[bh*16 + chunk] = red[0];
  __syncthreads();
  red[tid] = s2; __syncthreads();
  for(int o = 128; o > 0; o >>= 1){ if(tid < o) red[tid] = fmax(red[tid], red[tid+o]); __syncthreads(); }
  if(tid == 0) kmaxp[bh*16 + chunk] = red[0];
}

__global__ void k_mqk(const double* __restrict__ qmaxp, const double* __restrict__ kmaxp,
                      double* __restrict__ mqk2){
  int bh = blockIdx.x;
  if(threadIdx.x == 0){
    double mq = -1e300, mk = -1e300;
    for(int i = 0; i < 16; i++){ mq = fmax(mq, qmaxp[bh*16 + i]); mk = fmax(mk, kmaxp[bh*16 + i]); }
    mqk2[bh] = mq + mk;
  }
}

// ---------------- K2: E2LSH hashes (float64) ----------------
__global__ void k_hash(const float* __restrict__ q, const float* __restrict__ kk,
                       const float* __restrict__ alpha, const float* __restrict__ beta,
                       const double* __restrict__ qn2d, const double* __restrict__ kn2d,
                       const double* __restrict__ mqk2,
                       double* __restrict__ qh, double* __restrict__ kh){
  __shared__ double al[264];
  __shared__ double be[4];
  int tid = threadIdx.x;
  for(int i = tid; i < 264; i += 256) al[i] = (double)alpha[i];
  if(tid < 4) be[tid] = (double)beta[tid];
  __syncthreads();
  int gid = blockIdx.x*256 + tid;
  int side = gid >> 16; int r = gid & 65535;
  int bh = r >> 12, t = r & 4095;
  int b = bh >> 3, hh = bh & 7;
  const float* x = (side ? kk : q) + (((size_t)(b*TT + t)*TH) + hh)*TE;
  const float4* xr = (const float4*)x;
  double a0 = 0.0, a1 = 0.0, a2 = 0.0, a3 = 0.0;
  #pragma unroll
  for(int c = 0; c < 16; c++){
    float4 vv = xr[c];
    const double* a = al + c*16;
    a0 += (double)vv.x*a[0]  + (double)vv.y*a[4]  + (double)vv.z*a[8]  + (double)vv.w*a[12];
    a1 += (double)vv.x*a[1]  + (double)vv.y*a[5]  + (double)vv.z*a[9]  + (double)vv.w*a[13];
    a2 += (double)vv.x*a[2]  + (double)vv.y*a[6]  + (double)vv.z*a[10] + (double)vv.w*a[14];
    a3 += (double)vv.x*a[3]  + (double)vv.y*a[7]  + (double)vv.z*a[11] + (double)vv.w*a[15];
  }
  double n2  = (side ? kn2d : qn2d)[bh*TT + t];
  double ext = sqrt(fmax(mqk2[bh] - n2, 0.0));
  int ec = side ? 65 : 64;
  double* dst = side ? kh : qh;
  dst[((size_t)0*TBH + bh)*TT + t] = a0 + ext*al[ec*4 + 0] + be[0];
  dst[((size_t)1*TBH + bh)*TT + t] = a1 + ext*al[ec*4 + 1] + be[1];
  dst[((size_t)2*TBH + bh)*TT + t] = a2 + ext*al[ec*4 + 2] + be[2];
  dst[((size_t)3*TBH + bh)*TT + t] = a3 + ext*al[ec*4 + 3] + be[3];
}

// ---------------- K3: stable argsort via bitonic on doubles (1024 thr) ----------------
__global__ void k_sort(const double* __restrict__ qh, const double* __restrict__ kh,
                       int* __restrict__ qpos, int* __restrict__ kpos,
                       int* __restrict__ qrev, int* __restrict__ krev){
  __shared__ double v[4096];
  __shared__ int    ix[4096];
  int blk = blockIdx.x; int side = blk >> 6; int hb = blk & 63;
  const double* src = (side ? kh : qh) + (size_t)hb*TT;
  int tid = threadIdx.x;
  for(int i = tid; i < 4096; i += 1024){ v[i] = src[i]; ix[i] = i; }
  __syncthreads();
  for(int k = 2; k <= 4096; k <<= 1){
    for(int j = k >> 1; j > 0; j >>= 1){
      for(int i = tid; i < 4096; i += 1024){
        int l = i ^ j;
        if(l > i){
          double va = v[i], vb = v[l]; int ia = ix[i], ib = ix[l];
          bool gt  = (va > vb) || (va == vb && ia > ib);
          bool asc = ((i & k) == 0);
          if(gt == asc){ v[i] = vb; v[l] = va; ix[i] = ib; ix[l] = ia; }
        }
      }
      __syncthreads();
    }
  }
  int* pos = (side ? kpos : qpos) + (size_t)hb*TT;
  int* rev = (side ? krev : qrev) + (size_t)hb*TT;
  for(int i = tid; i < 4096; i += 1024){ int id = ix[i]; pos[i] = id; rev[id] = i; }
}

// ---------------- K4: dash GEMM (both sides) -> dash[bh][t][m] ----------------
// 512 threads, 128 t-rows/block, 8 waves/CU. fp32 chain e-ascending (bit-identical).
__launch_bounds__(512, 1)
__global__ void k_dash(const float* __restrict__ q, const float* __restrict__ kk,
                       const float* __restrict__ proj,
                       const float* __restrict__ qn2f, const float* __restrict__ kn2f,
                       float* __restrict__ qdash, float* __restrict__ kdash){
  __shared__ __align__(16) float pjL[64*260];    // 66.6 KB
  __shared__ __align__(16) float x_l[128*68];    // 34.8 KB
  __shared__ float x_n[128];
  int tid = threadIdx.x;
  int bx = blockIdx.x;
  int side = bx >> 9; int r = bx & 511; int bh = r >> 5; int ch = r & 31;
  int b = bh >> 3, hh = bh & 7, t0 = ch*128;
  const float* x  = side ? kk   : q;
  const float* n2 = side ? kn2f : qn2f;
  float* outp     = side ? kdash : qdash;

  #pragma unroll 8
  for(int it = 0; it < 32; it++){
    int idx = it*512 + tid;
    pjL[(idx & 63)*260 + (idx >> 6)] = proj[idx];
  }
  {
    int rr = tid >> 2, c = tid & 3;
    const float4* src = (const float4*)(x + (((size_t)(b*TT + t0 + rr)*TH) + hh)*TE);
    float4* dst = (float4*)(x_l + rr*68);
    #pragma unroll
    for(int i = 0; i < 4; i++) dst[c*4 + i] = src[c*4 + i];
  }
  if(tid < 128) x_n[tid] = n2[bh*TT + t0 + tid];
  __syncthreads();

  int ml = (tid & 15)*4;
  int tb = tid >> 4;   // 0..31
  float4 acc[4][4];
  #pragma unroll
  for(int tt = 0; tt < 4; tt++)
    #pragma unroll
    for(int g = 0; g < 4; g++) acc[tt][g] = make_float4(0.f,0.f,0.f,0.f);

  #pragma unroll 4
  for(int k4 = 0; k4 < 16; k4++){
    float4 xv[4];
    #pragma unroll
    for(int tt = 0; tt < 4; tt++)
      xv[tt] = *((const float4*)(x_l + (tb + 32*tt)*68 + k4*4));
    #pragma unroll
    for(int kk4 = 0; kk4 < 4; kk4++){
      int krow = k4*4 + kk4;
      #pragma unroll
      for(int g = 0; g < 4; g++){
        float4 pv = *((const float4*)(pjL + krow*260 + ml + 64*g));
        #pragma unroll
        for(int tt = 0; tt < 4; tt++){
          float xs = (kk4 == 0) ? xv[tt].x : (kk4 == 1) ? xv[tt].y : (kk4 == 2) ? xv[tt].z : xv[tt].w;
          acc[tt][g].x = fmaf(xs, pv.x, acc[tt][g].x);
          acc[tt][g].y = fmaf(xs, pv.y, acc[tt][g].y);
          acc[tt][g].z = fmaf(xs, pv.z, acc[tt][g].z);
          acc[tt][g].w = fmaf(xs, pv.w, acc[tt][g].w);
        }
      }
    }
  }
  #pragma unroll
  for(int tt = 0; tt < 4; tt++){
    int t_r = tb + 32*tt;
    float diag = 0.5f*C_TEMP*x_n[t_r];
    size_t rowbase = ((size_t)bh*TT + t0 + t_r)*256;
    #pragma unroll
    for(int g = 0; g < 4; g++){
      float4 a = acc[tt][g];
      float4 dd;
      dd.x = fmaf(C_DN, a.x, -diag); dd.y = fmaf(C_DN, a.y, -diag);
      dd.z = fmaf(C_DN, a.z, -diag); dd.w = fmaf(C_DN, a.w, -diag);
      *((float4*)(outp + rowbase + ml + 64*g)) = dd;
    }
  }
}

// ---------------- K4b: max over dashK chunks -> klsp ----------------
__global__ void k_klsmax(const float* __restrict__ kdash, float* __restrict__ klsp){
  __shared__ float wr[4];
  int tid = threadIdx.x;
  int bx = blockIdx.x; int bh = bx >> 7, ch = bx & 127;
  const float4* src = (const float4*)(kdash + ((size_t)bh << 20)) + ch*2048;
  float mx = -1e30f;
  #pragma unroll
  for(int i = 0; i < 8; i++){
    float4 vv = src[i*256 + tid];
    mx = fmaxf(mx, fmaxf(fmaxf(vv.x, vv.y), fmaxf(vv.z, vv.w)));
  }
  #pragma unroll
  for(int o = 32; o > 0; o >>= 1) mx = fmaxf(mx, __shfl_xor(mx, o, 64));
  if((tid & 63) == 0) wr[tid >> 6] = mx;
  __syncthreads();
  if(tid == 0) klsp[bh*128 + ch] = fmaxf(fmaxf(wr[0], wr[1]), fmaxf(wr[2], wr[3]));
}

__global__ void k_klsred(const float* __restrict__ klsp, float* __restrict__ kls){
  __shared__ float red[2];
  int bh = blockIdx.x, tid = threadIdx.x;
  float v = klsp[bh*128 + tid];
  #pragma unroll
  for(int o = 32; o > 0; o >>= 1) v = fmaxf(v, __shfl_xor(v, o, 64));
  if((tid & 63) == 0) red[tid >> 6] = v;
  __syncthreads();
  if(tid == 0) kls[bh] = fmaxf(red[0], red[1]);
}

// ---------------- K4c: kp = exp(dashK - kls)*ratio, in place ----------------
__global__ void k_expk(float* __restrict__ kp, const float* __restrict__ kls){
  int tid = threadIdx.x; int blk = blockIdx.x;
  float4* p = (float4*)kp;
  size_t base = (size_t)blk*2048;
  float stab = kls[blk >> 7];
  #pragma unroll
  for(int i = 0; i < 8; i++){
    size_t ix = base + i*256 + tid;
    float4 vv = p[ix];
    vv.x = __expf(vv.x - stab)*C_RATIO; vv.y = __expf(vv.y - stab)*C_RATIO;
    vv.z = __expf(vv.z - stab)*C_RATIO; vv.w = __expf(vv.w - stab)*C_RATIO;
    p[ix] = vv;
  }
}

// ---------------- K4d: qp = exp(dashQ - rowmax)*ratio in place, pls = rowmax ----------------
__global__ void k_expq(float* __restrict__ qp, float* __restrict__ pls){
  int tid = threadIdx.x, wid = tid >> 6, lane = tid & 63;
  int row = blockIdx.x*4 + wid;
  float4* p = (float4*)(qp + (size_t)row*256);
  float4 vv = p[lane];
  float mr = fmaxf(fmaxf(vv.x, vv.y), fmaxf(vv.z, vv.w));
  #pragma unroll
  for(int o = 32; o > 0; o >>= 1) mr = fmaxf(mr, __shfl_xor(mr, o, 64));
  float4 rr;
  rr.x = __expf(vv.x - mr)*C_RATIO; rr.y = __expf(vv.y - mr)*C_RATIO;
  rr.z = __expf(vv.z - mr)*C_RATIO; rr.w = __expf(vv.w - mr)*C_RATIO;
  p[lane] = rr;
  if(lane == 0) pls[row] = mr;
}

// ---------------- K5: kv partials over s-chunks, then reduce ----------------
__global__ void k_kv2(const float* __restrict__ kp, const float* __restrict__ v,
                      float* __restrict__ kvp, float* __restrict__ ksump){
  int bx = blockIdx.x; int sc = bx >> 7; int rem = bx & 127; int bh = rem >> 3; int mt = rem & 7;
  int tid = threadIdx.x; int g = tid >> 6, d = tid & 63;
  int b = bh >> 3, hh = bh & 7; int m0 = mt*32;
  float a[8], sa[8];
  #pragma unroll
  for(int j = 0; j < 8; j++){ a[j] = 0.f; sa[j] = 0.f; }
  const float* kpb = kp + (size_t)bh*TT*256 + m0 + g;
  const float* vb  = v + (size_t)b*TT*TH*TE + hh*TE + d;
  int s0 = sc*1024;
  #pragma unroll 4
  for(int s = s0; s < s0 + 1024; s++){
    float vv = vb[(size_t)s*512];
    const float* kr = kpb + (size_t)s*256;
    #pragma unroll
    for(int j = 0; j < 8; j++){
      float kj = kr[4*j];
      a[j] = fmaf(kj, vv, a[j]); sa[j] += kj;
    }
  }
  #pragma unroll
  for(int j = 0; j < 8; j++){
    int m = m0 + g + 4*j;
    kvp[(((size_t)sc*16 + bh)*256 + m)*64 + d] = a[j];
    if(d == 0) ksump[((size_t)sc*16 + bh)*256 + m] = sa[j];
  }
}

__global__ void k_kvred(const float* __restrict__ kvp, const float* __restrict__ ksump,
                        float* __restrict__ kv, float* __restrict__ ksum){
  int bx = blockIdx.x, tid = threadIdx.x;
  if(bx < 256){
    size_t i = (size_t)bx*1024 + tid*4;
    float4 s = make_float4(0.f,0.f,0.f,0.f);
    #pragma unroll
    for(int sc = 0; sc < 4; sc++){
      float4 p = *((const float4*)(kvp + (size_t)sc*262144 + i));
      s.x += p.x; s.y += p.y; s.z += p.z; s.w += p.w;
    }
    *((float4*)(kv + i)) = s;
  } else {
    for(int m = tid; m < 4096; m += 256){
      float s = 0.f;
      #pragma unroll
      for(int sc = 0; sc < 4; sc++) s += ksump[sc*4096 + m];
      ksum[m] = s;
    }
  }
}

// ---------------- K6: per-bucket attention, MFMA split-bf16 ----------------
__launch_bounds__(256, 2)
__global__ void k_bucket(const float* __restrict__ q, const float* __restrict__ kk, const float* __restrict__ v,
                         const float* __restrict__ qp, const float* __restrict__ kp,
                         const int* __restrict__ qpos, const int* __restrict__ kpos,
                         const int* __restrict__ qrev, const int* __restrict__ krev,
                         const float* __restrict__ pls, const float* __restrict__ kls,
                         const float* __restrict__ qn2f, const float* __restrict__ kn2f,
                         float* __restrict__ o_t, float* __restrict__ lse_t, float* __restrict__ dsum_t){
  __shared__ __align__(16) char smem[73232];
  constexpr int OFS_B = 34816;
  int* qidxL   = (int*)(smem + 69632);
  int* kidxL   = (int*)(smem + 70144);
  int* qbpL    = (int*)(smem + 70656);
  int* kbpL    = (int*)(smem + 71168);
  float* lseL  = (float*)(smem + 71680);
  float* pfacL = (float*)(smem + 72192);
  float* kn2L  = (float*)(smem + 72704);
  float* kmaxP = (float*)(smem + 73216);

  int tid = threadIdx.x;
  int w = tid >> 6, lane = tid & 63, l15 = lane & 15, quad = lane >> 4;
  int bx = blockIdx.x; int n = bx & 31, bh = (bx >> 5) & 15, h = bx >> 9;
  int b = bh >> 3, hh = bh & 7;

  if(tid < 128){
    int tk = kpos[((size_t)h*TBH + bh)*TT + n*128 + tid];
    kidxL[tid] = tk;
    int pk = 0;
    #pragma unroll
    for(int h3 = 0; h3 < 4; h3++){ int rv = krev[((size_t)h3*TBH + bh)*TT + tk]; pk |= (rv >> 7) << (8*h3); }
    kbpL[tid] = pk;
    kn2L[tid] = kn2f[(size_t)bh*TT + tk];
    int tq = qpos[((size_t)h*TBH + bh)*TT + n*128 + tid];
    qidxL[tid] = tq;
    int pq = 0;
    #pragma unroll
    for(int h3 = 0; h3 < 4; h3++){ int rv = qrev[((size_t)h3*TBH + bh)*TT + tq]; pq |= (rv >> 7) << (8*h3); }
    qbpL[tid] = pq;
  }
  __syncthreads();
  if(tid < 64){
    float m = fmaxf(kn2L[tid], kn2L[tid + 64]);
    #pragma unroll
    for(int o = 32; o > 0; o >>= 1) m = fmaxf(m, __shfl_xor(m, o, 64));
    if(tid == 0) kmaxP[0] = m;
  }
  {  // stage Q into bufA, K into bufB (bf16 hi/lo)
    int r = tid >> 1, hf = tid & 1;
    const float4* qs = (const float4*)(q  + (((size_t)(b*TT + qidxL[r])*TH) + hh)*TE) + hf*8;
    const float4* ks = (const float4*)(kk + (((size_t)(b*TT + kidxL[r])*TH) + hh)*TE) + hf*8;
    stage64(smem + r*272, qs, hf);
    stage64(smem + OFS_B + r*272, ks, hf);
  }
  __syncthreads();
  if(tid < 128){  // per-row stabilizer (Cauchy-Schwarz UB) + pfac
    int tq = qidxL[tid];
    float plsv = pls[(size_t)bh*TT + tq] + kls[bh];
    float lse = fmaxf(plsv, C_TEMP * sqrtf(qn2f[(size_t)bh*TT + tq] * kmaxP[0]));
    lseL[tid] = lse;
    pfacL[tid] = __expf(plsv - lse);
  }

  f32x4 acc_s[2][8], acc_p[2][8];
  #pragma unroll
  for(int mt = 0; mt < 2; mt++)
    #pragma unroll
    for(int nt = 0; nt < 8; nt++){
      acc_s[mt][nt] = (f32x4){0.f,0.f,0.f,0.f};
      acc_p[mt][nt] = (f32x4){0.f,0.f,0.f,0.f};
    }

  {  // S = Q K^T (K=64, split-3)
    bf16x8 ahi[2][2], alo[2][2];
    #pragma unroll
    for(int mt = 0; mt < 2; mt++)
      #pragma unroll
      for(int ks = 0; ks < 2; ks++){
        const char* ap = smem + (32*w + 16*mt + l15)*272 + 64*ks + 16*quad;
        ahi[mt][ks] = *((const bf16x8*)ap);
        alo[mt][ks] = *((const bf16x8*)(ap + 128));
      }
    #pragma unroll
    for(int nt = 0; nt < 8; nt++){
      #pragma unroll
      for(int ks = 0; ks < 2; ks++){
        const char* bp = smem + OFS_B + (16*nt + l15)*272 + 64*ks + 16*quad;
        bf16x8 bhi = *((const bf16x8*)bp);
        bf16x8 blo = *((const bf16x8*)(bp + 128));
        #pragma unroll
        for(int mt = 0; mt < 2; mt++){
          acc_s[mt][nt] = __builtin_amdgcn_mfma_f32_16x16x32_bf16(ahi[mt][ks], bhi, acc_s[mt][nt], 0, 0, 0);
          acc_s[mt][nt] = __builtin_amdgcn_mfma_f32_16x16x32_bf16(ahi[mt][ks], blo, acc_s[mt][nt], 0, 0, 0);
          acc_s[mt][nt] = __builtin_amdgcn_mfma_f32_16x16x32_bf16(alo[mt][ks], bhi, acc_s[mt][nt], 0, 0, 0);
        }
      }
    }
  }
  __syncthreads();

  // DP = QP KP^T (K=256 in 4 chunks of 64, split-3)
  for(int c = 0; c < 4; c++){
    { int r = tid >> 1, hf = tid & 1;
      const float4* qs = (const float4*)(qp + ((size_t)bh*TT + qidxL[r])*256 + c*64) + hf*8;
      const float4* ks = (const float4*)(kp + ((size_t)bh*TT + kidxL[r])*256 + c*64) + hf*8;
      stage64(smem + r*272, qs, hf);
      stage64(smem + OFS_B + r*272, ks, hf);
    }
    __syncthreads();
    bf16x8 ahi[2][2], alo[2][2];
    #pragma unroll
    for(int mt = 0; mt < 2; mt++)
      #pragma unroll
      for(int ks = 0; ks < 2; ks++){
        const char* ap = smem + (32*w + 16*mt + l15)*272 + 64*ks + 16*quad;
        ahi[mt][ks] = *((const bf16x8*)ap);
        alo[mt][ks] = *((const bf16x8*)(ap + 128));
      }
    #pragma unroll
    for(int nt = 0; nt < 8; nt++){
      #pragma unroll
      for(int ks = 0; ks < 2; ks++){
        const char* bp = smem + OFS_B + (16*nt + l15)*272 + 64*ks + 16*quad;
        bf16x8 bhi = *((const bf16x8*)bp);
        bf16x8 blo = *((const bf16x8*)(bp + 128));
        #pragma unroll
        for(int mt = 0; mt < 2; mt++){
          acc_p[mt][nt] = __builtin_amdgcn_mfma_f32_16x16x32_bf16(ahi[mt][ks], bhi, acc_p[mt][nt], 0, 0, 0);
          acc_p[mt][nt] = __builtin_amdgcn_mfma_f32_16x16x32_bf16(ahi[mt][ks], blo, acc_p[mt][nt], 0, 0, 0);
          acc_p[mt][nt] = __builtin_amdgcn_mfma_f32_16x16x32_bf16(alo[mt][ks], bhi, acc_p[mt][nt], 0, 0, 0);
        }
      }
    }
    __syncthreads();
  }

  {  // stage V^T into bufB (bf16 hi/lo, transposed)
    int j = tid >> 1, hc = tid & 1;
    const float4* vs = (const float4*)(v + (((size_t)(b*TT + kidxL[j])*TH) + hh)*TE) + hc*8;
    #pragma unroll
    for(int x = 0; x < 8; x++){
      float4 vv = vs[x];
      int c0 = hc*32 + 4*x;
      float vals[4] = {vv.x, vv.y, vv.z, vv.w};
      #pragma unroll
      for(int i = 0; i < 4; i++){
        uint16_t hi = f2bf(vals[i]);
        float lo = vals[i] - bf2f(hi);
        *((uint16_t*)(smem + OFS_B + (c0 + i)*528 + 2*j)) = hi;
        *((uint16_t*)(smem + OFS_B + (c0 + i)*528 + 256 + 2*j)) = f2bf(lo);
      }
    }
  }
  int qbp_r[8]; float lse_r[8], pfac_r[8], dsump[8]; int kbp_c[8];
  #pragma unroll
  for(int i = 0; i < 8; i++){
    int r = 32*w + 16*(i >> 2) + 4*quad + (i & 3);
    qbp_r[i] = qbpL[r]; lse_r[i] = lseL[r]; pfac_r[i] = pfacL[r]; dsump[i] = 0.f;
  }
  #pragma unroll
  for(int nt = 0; nt < 8; nt++) kbp_c[nt] = kbpL[l15 + 16*nt];
  __syncthreads();

  // D (elementwise in C-layout regs) -> LDS bf16 hi/lo -> O += D V (two col-halves)
  f32x4 acc_o[2][4];
  #pragma unroll
  for(int mt = 0; mt < 2; mt++)
    #pragma unroll
    for(int nv = 0; nv < 4; nv++) acc_o[mt][nv] = (f32x4){0.f,0.f,0.f,0.f};

  #pragma unroll
  for(int hv = 0; hv < 2; hv++){
    #pragma unroll
    for(int nt = 0; nt < 4; nt++){
      int ntg = 4*hv + nt;
      #pragma unroll
      for(int mt = 0; mt < 2; mt++){
        f32x4 s4 = acc_s[mt][ntg], p4 = acc_p[mt][ntg];
        #pragma unroll
        for(int e = 0; e < 4; e++){
          int i = mt*4 + e;
          int du = dupc((uint32_t)(qbp_r[i] ^ kbp_c[ntg]));
          float ein  = __expf(fmaf(C_TEMP, s4[e], -lndup(du)) - lse_r[i]);
          float dots = fmaf(-p4[e]*rcpdup(du), pfac_r[i], ein);
          dsump[i] += dots;
          int row = 32*w + 16*mt + 4*quad + e;
          int colL = l15 + 16*nt;
          uint16_t hi = f2bf(dots);
          float lo = dots - bf2f(hi);
          *((uint16_t*)(smem + row*272 + 2*colL)) = hi;
          *((uint16_t*)(smem + row*272 + 128 + 2*colL)) = f2bf(lo);
        }
      }
    }
    // O MFMAs for this k-half (each wave reads only its own D rows -> no barrier needed)
    bf16x8 dhi[2][2], dlo[2][2];
    #pragma unroll
    for(int mt = 0; mt < 2; mt++)
      #pragma unroll
      for(int ks = 0; ks < 2; ks++){
        const char* ap = smem + (32*w + 16*mt + l15)*272 + 64*ks + 16*quad;
        dhi[mt][ks] = *((const bf16x8*)ap);
        dlo[mt][ks] = *((const bf16x8*)(ap + 128));
      }
    #pragma unroll
    for(int nv = 0; nv < 4; nv++){
      #pragma unroll
      for(int ks = 0; ks < 2; ks++){
        const char* bp = smem + OFS_B + (16*nv + l15)*528 + 128*hv + 64*ks + 16*quad;
        bf16x8 vhi = *((const bf16x8*)bp);
        bf16x8 vlo = *((const bf16x8*)(bp + 256));
        #pragma unroll
        for(int mt = 0; mt < 2; mt++){
          acc_o[mt][nv] = __builtin_amdgcn_mfma_f32_16x16x32_bf16(dhi[mt][ks], vhi, acc_o[mt][nv], 0, 0, 0);
          acc_o[mt][nv] = __builtin_amdgcn_mfma_f32_16x16x32_bf16(dhi[mt][ks], vlo, acc_o[mt][nv], 0, 0, 0);
          acc_o[mt][nv] = __builtin_amdgcn_mfma_f32_16x16x32_bf16(dlo[mt][ks], vhi, acc_o[mt][nv], 0, 0, 0);
        }
      }
    }
  }

  // epilogue
  #pragma unroll
  for(int i = 0; i < 8; i++){
    float s = dsump[i];
    s += __shfl_xor(s, 1, 64); s += __shfl_xor(s, 2, 64);
    s += __shfl_xor(s, 4, 64); s += __shfl_xor(s, 8, 64);
    dsump[i] = s;
  }
  size_t obase = ((size_t)h*TBH + bh)*TT;
  if(l15 == 0){
    #pragma unroll
    for(int i = 0; i < 8; i++){
      int r = 32*w + 16*(i >> 2) + 4*quad + (i & 3);
      int tq = qidxL[r];
      lse_t [obase + tq] = lse_r[i];
      dsum_t[obase + tq] = dsump[i];
    }
  }
  #pragma unroll
  for(int mt = 0; mt < 2; mt++){
    #pragma unroll
    for(int e = 0; e < 4; e++){
      int r = 32*w + 16*mt + 4*quad + e;
      int tq = qidxL[r];
      float* orow = o_t + (obase + tq)*64;
      #pragma unroll
      for(int nv = 0; nv < 4; nv++) orow[l15 + 16*nv] = acc_o[mt][nv][e];
    }
  }
}

// ---------------- K7: fused qkv GEMM + hash-round combine ----------------
// Per block: one bh, 128 t-rows. qkv = qp @ kv via register-tiled VALU GEMM
// (kv+ksum staged once in LDS), then combine epilogue. 512 thr, 8 waves/CU.
__launch_bounds__(512, 1)
__global__ void k_final2(const float* __restrict__ qp, const float* __restrict__ kv,
                         const float* __restrict__ ksum, const float* __restrict__ o_t,
                         const float* __restrict__ lse_t, const float* __restrict__ dsum_t,
                         const float* __restrict__ pls, const float* __restrict__ kls,
                         float* __restrict__ out){
  __shared__ __align__(16) float kv_l[256*68];   // [m][d], col 64 = ksum (68.0 KB)
  __shared__ __align__(16) float qp_l[128*68];   // [r][64-m chunk] (34.8 KB)
  __shared__ float prL[128][4];
  __shared__ float pscL[128];
  __shared__ float nrmL[128];
  int tid = threadIdx.x;
  int bx = blockIdx.x; int bh = bx >> 5, ch = bx & 31;
  int b = bh >> 3, hh = bh & 7;
  int t0 = ch*128;
  {
    const float4* kv4 = (const float4*)(kv + (size_t)bh*16384);
    #pragma unroll
    for(int i = 0; i < 8; i++){
      int idx = i*512 + tid;
      int m = idx >> 4, d4 = idx & 15;
      *((float4*)(kv_l + m*68 + d4*4)) = kv4[idx];
    }
    if(tid < 256) kv_l[tid*68 + 64] = ksum[bh*256 + tid];
  }
  int c = tid & 15, tb = tid >> 4;   // c: d-group (4 cols), tb: 0..31
  float4 acc[4];
  #pragma unroll
  for(int tt = 0; tt < 4; tt++) acc[tt] = make_float4(0.f,0.f,0.f,0.f);
  float p1 = 0.f;
  for(int c4 = 0; c4 < 4; c4++){
    __syncthreads();
    #pragma unroll
    for(int it = 0; it < 4; it++){
      int r = it*32 + tb;
      *((float4*)(qp_l + r*68 + c*4)) =
        *((const float4*)(qp + ((size_t)bh*TT + t0 + r)*256 + c4*64 + c*4));
    }
    __syncthreads();
    #pragma unroll 4
    for(int m4 = 0; m4 < 16; m4++){
      float4 qv[4];
      #pragma unroll
      for(int tt = 0; tt < 4; tt++)
        qv[tt] = *((const float4*)(qp_l + (tb + 32*tt)*68 + m4*4));
      #pragma unroll
      for(int mm = 0; mm < 4; mm++){
        int m = c4*64 + m4*4 + mm;
        float4 kvv = *((const float4*)(kv_l + m*68 + c*4));
        #pragma unroll
        for(int tt = 0; tt < 4; tt++){
          float qs = (mm == 0) ? qv[tt].x : (mm == 1) ? qv[tt].y : (mm == 2) ? qv[tt].z : qv[tt].w;
          acc[tt].x = fmaf(qs, kvv.x, acc[tt].x);
          acc[tt].y = fmaf(qs, kvv.y, acc[tt].y);
          acc[tt].z = fmaf(qs, kvv.z, acc[tt].z);
          acc[tt].w = fmaf(qs, kvv.w, acc[tt].w);
        }
      }
    }
    if(tid < 128){   // p1 partial for row tid over this m-chunk (ascending m)
      #pragma unroll 8
      for(int m = 0; m < 64; m++)
        p1 = fmaf(qp_l[tid*68 + m], kv_l[(c4*64 + m)*68 + 64], p1);
    }
  }
  __syncthreads();
  if(tid < 128){   // per-row combine scalars
    int t = t0 + tid;
    float l0 = lse_t[((size_t)0*TBH + bh)*TT + t], l1 = lse_t[((size_t)1*TBH + bh)*TT + t];
    float l2 = lse_t[((size_t)2*TBH + bh)*TT + t], l3 = lse_t[((size_t)3*TBH + bh)*TT + t];
    float M = fmaxf(fmaxf(l0, l1), fmaxf(l2, l3));
    float e0 = __expf(l0 - M), e1 = __expf(l1 - M), e2 = __expf(l2 - M), e3 = __expf(l3 - M);
    float rs = 1.f / (e0 + e1 + e2 + e3);
    float pr0 = e0*rs, pr1 = e1*rs, pr2 = e2*rs, pr3 = e3*rs;
    float psc = __expf(pls[bh*TT + t] + kls[bh] - M)*rs;
    float nrm = 0.f;
    nrm = fmaf(dsum_t[((size_t)0*TBH + bh)*TT + t], pr0, nrm);
    nrm = fmaf(dsum_t[((size_t)1*TBH + bh)*TT + t], pr1, nrm);
    nrm = fmaf(dsum_t[((size_t)2*TBH + bh)*TT + t], pr2, nrm);
    nrm = fmaf(dsum_t[((size_t)3*TBH + bh)*TT + t], pr3, nrm);
    nrm = fmaf(p1, psc, nrm);
    prL[tid][0] = pr0; prL[tid][1] = pr1; prL[tid][2] = pr2; prL[tid][3] = pr3;
    pscL[tid] = psc;
    nrmL[tid] = fmaxf(nrm, 1e-6f);
  }
  __syncthreads();
  #pragma unroll
  for(int tt = 0; tt < 4; tt++){
    int r = tb + 32*tt; int t = t0 + r;
    float4 o0 = *((const float4*)(o_t + (((size_t)0*TBH + bh)*TT + t)*64 + c*4));
    float4 o1 = *((const float4*)(o_t + (((size_t)1*TBH + bh)*TT + t)*64 + c*4));
    float4 o2 = *((const float4*)(o_t + (((size_t)2*TBH + bh)*TT + t)*64 + c*4));
    float4 o3 = *((const float4*)(o_t + (((size_t)3*TBH + bh)*TT + t)*64 + c*4));
    float pr0 = prL[r][0], pr1 = prL[r][1], pr2 = prL[r][2], pr3 = prL[r][3];
    float psc = pscL[r], nrm = nrmL[r];
    float4 outl;
    outl.x = fmaf(o3.x, pr3, fmaf(o2.x, pr2, fmaf(o1.x, pr1, o0.x*pr0)));
    outl.y = fmaf(o3.y, pr3, fmaf(o2.y, pr2, fmaf(o1.y, pr1, o0.y*pr0)));
    outl.z = fmaf(o3.z, pr3, fmaf(o2.z, pr2, fmaf(o1.z, pr1, o0.z*pr0)));
    outl.w = fmaf(o3.w, pr3, fmaf(o2.w, pr2, fmaf(o1.w, pr1, o0.w*pr0)));
    float4 res;
    res.x = (outl.x + acc[tt].x*psc) / nrm;
    res.y = (outl.y + acc[tt].y*psc) / nrm;
    res.z = (outl.z + acc[tt].z*psc) / nrm;
    res.w = (outl.w + acc[tt].w*psc) / nrm;
    *((float4*)(out + ((size_t)(b*TT + t)*TH + hh)*64 + c*4)) = res;
  }
}

// sentinel: signals ws_size-too-small distinctly from a numeric bug
__global__ void k_sentinel(float* __restrict__ out, int n){
  int i = blockIdx.x*256 + threadIdx.x;
  if(i < n) out[i] = 12345.0f;
}

extern "C" void kernel_launch(void* const* d_in, const int* in_sizes, int n_in,
                              void* d_out, int out_size, void* d_ws, size_t ws_size,
                              hipStream_t stream){
  const float* q     = (const float*)d_in[0];
  const float* k     = (const float*)d_in[1];
  const float* v     = (const float*)d_in[2];
  const float* proj  = (const float*)d_in[3];
  const float* alpha = (const float*)d_in[4];
  const float* beta  = (const float*)d_in[5];
  float* out = (float*)d_out;
  char* ws = (char*)d_ws;

  if(ws_size < WS_NEED){
    k_sentinel<<<dim3((out_size + 255)/256), dim3(256), 0, stream>>>(out, out_size);
    return;
  }

  float*  qn2f  = (float*) (ws + OFF_QN2F);
  float*  kn2f  = (float*) (ws + OFF_KN2F);
  double* qn2d  = (double*)(ws + OFF_QN2D);
  double* kn2d  = (double*)(ws + OFF_KN2D);
  double* mqk2  = (double*)(ws + OFF_MQK2);
  double* qmaxp = (double*)(ws + OFF_QMAXP);
  double* kmaxp = (double*)(ws + OFF_KMAXP);
  double* qh    = (double*)(ws + OFF_QH);
  double* kh    = (double*)(ws + OFF_KH);
  int*   qpos   = (int*)  (ws + OFF_QPOS);
  int*   kpos   = (int*)  (ws + OFF_KPOS);
  int*   qrev   = (int*)  (ws + OFF_QREV);
  int*   krev   = (int*)  (ws + OFF_KREV);
  float* klsp   = (float*)(ws + OFF_KLSP);
  float* kls    = (float*)(ws + OFF_KLS);
  float* qp     = (float*)(ws + OFF_QP);   // doubles as dashQ
  float* kp     = (float*)(ws + OFF_KP);   // doubles as dashK
  float* pls    = (float*)(ws + OFF_PLS);
  float* ksum   = (float*)(ws + OFF_KSUM);
  float* kvv    = (float*)(ws + OFF_KV);
  float* o_t    = (float*)(ws + OFF_OT);
  float* lse_t  = (float*)(ws + OFF_LSET);
  float* dsum_t = (float*)(ws + OFF_DSUM);
  float* kvp    = (float*)(ws + OFF_KVP);  // overlays dead qn2d/kn2d/qh/kh
  float* ksump  = (float*)(ws + OFF_KSP);

  k_norms2<<<dim3(256),   dim3(256),  0, stream>>>(q, k, qn2f, kn2f, qn2d, kn2d, qmaxp, kmaxp);
  k_mqk   <<<dim3(16),    dim3(64),   0, stream>>>(qmaxp, kmaxp, mqk2);
  k_hash  <<<dim3(512),   dim3(256),  0, stream>>>(q, k, alpha, beta, qn2d, kn2d, mqk2, qh, kh);
  k_sort  <<<dim3(128),   dim3(1024), 0, stream>>>(qh, kh, qpos, kpos, qrev, krev);
  k_dash  <<<dim3(1024),  dim3(512),  0, stream>>>(q, k, proj, qn2f, kn2f, qp, kp);
  k_klsmax<<<dim3(2048),  dim3(256),  0, stream>>>(kp, klsp);
  k_klsred<<<dim3(16),    dim3(128),  0, stream>>>(klsp, kls);
  k_expk  <<<dim3(2048),  dim3(256),  0, stream>>>(kp, kls);
  k_expq  <<<dim3(16384), dim3(256),  0, stream>>>(qp, pls);
  k_kv2   <<<dim3(512),   dim3(256),  0, stream>>>(kp, v, kvp, ksump);
  k_kvred <<<dim3(257),   dim3(256),  0, stream>>>(kvp, ksump, kvv, ksum);
  k_bucket<<<dim3(2048),  dim3(256),  0, stream>>>(q, k, v, qp, kp, qpos, kpos, qrev, krev, pls, kls, qn2f, kn2f, o_t, lse_t, dsum_t);
  k_final2<<<dim3(512),   dim3(512),  0, stream>>>(qp, kvv, ksum, o_t, lse_t, dsum_t, pls, kls, out);
}